// Round 1
// baseline (1248.273 us; speedup 1.0000x reference)
//
#include <hip/hip_runtime.h>
#include <hip/hip_bf16.h>
#include <cmath>

// Problem constants
#define BATCH 2
#define LSEQ 2048
#define DMODEL 512
#define NHEADS 8
#define HD 64
#define RATIO 8
#define STRIDE 4
#define WINDOW 128
#define LC 511   // (2048-8)/4 + 1

// ---------------------------------------------------------------------------
// Generic fp32 GEMM: C[M,N] = A[M,K] * B[N,K]^T   (both row-major)
// 64x64 tile, 256 threads, 4x4 per thread, BK=16.
// ---------------------------------------------------------------------------
__global__ __launch_bounds__(256) void gemm_bt_f32(const float* __restrict__ A,
                                                   const float* __restrict__ B,
                                                   float* __restrict__ C,
                                                   int M, int N, int K) {
  __shared__ float As[16][64];
  __shared__ float Bs[16][64];
  const int tid = threadIdx.x;
  const int tx = tid & 15;   // col group 0..15
  const int ty = tid >> 4;   // row group 0..15
  const int bm = blockIdx.x * 64;
  const int bn = blockIdx.y * 64;
  const int lrow = tid >> 2;       // 0..63
  const int lk = (tid & 3) * 4;    // 0,4,8,12
  float acc[4][4] = {{0.f}};
  const int arow = bm + lrow;
  const int brow = bn + lrow;
  for (int k0 = 0; k0 < K; k0 += 16) {
    float4 a4 = make_float4(0.f, 0.f, 0.f, 0.f);
    float4 b4 = make_float4(0.f, 0.f, 0.f, 0.f);
    if (arow < M) a4 = *(const float4*)(A + (size_t)arow * K + k0 + lk);
    b4 = *(const float4*)(B + (size_t)brow * K + k0 + lk);  // N % 64 == 0 here
    As[lk + 0][lrow] = a4.x; As[lk + 1][lrow] = a4.y;
    As[lk + 2][lrow] = a4.z; As[lk + 3][lrow] = a4.w;
    Bs[lk + 0][lrow] = b4.x; Bs[lk + 1][lrow] = b4.y;
    Bs[lk + 2][lrow] = b4.z; Bs[lk + 3][lrow] = b4.w;
    __syncthreads();
#pragma unroll
    for (int kk = 0; kk < 16; ++kk) {
      const float4 av = *(const float4*)&As[kk][ty * 4];
      const float4 bv = *(const float4*)&Bs[kk][tx * 4];
      float a[4] = {av.x, av.y, av.z, av.w};
      float b[4] = {bv.x, bv.y, bv.z, bv.w};
#pragma unroll
      for (int i = 0; i < 4; ++i)
#pragma unroll
        for (int j = 0; j < 4; ++j) acc[i][j] += a[i] * b[j];
    }
    __syncthreads();
  }
#pragma unroll
  for (int i = 0; i < 4; ++i) {
    int row = bm + ty * 4 + i;
    if (row < M) {
#pragma unroll
      for (int j = 0; j < 4; ++j)
        C[(size_t)row * N + bn + tx * 4 + j] = acc[i][j];
    }
  }
}

// ---------------------------------------------------------------------------
// RoPE in-place on q and k.  idx over B*L*H*32.
// out[:32] = x1*cos - x2*sin ; out[32:] = x1*sin + x2*cos
// ---------------------------------------------------------------------------
__global__ void rope_kernel(float* __restrict__ q, float* __restrict__ k) {
  int idx = blockIdx.x * blockDim.x + threadIdx.x;
  const int total = BATCH * LSEQ * NHEADS * 32;
  if (idx >= total) return;
  int j = idx & 31;
  int h = (idx >> 5) & 7;
  int p = (idx >> 8) & 2047;
  int b = idx >> 19;  // 2048*8*32 = 2^19
  size_t base = ((size_t)(b * LSEQ + p)) * DMODEL + h * HD + j;
  // inv_freq = 10000^(-j/32) = exp(-j * ln(10000)/32)
  float inv_freq = expf(-(float)j * (9.210340371976184f / 32.f));
  float f = (float)p * inv_freq;
  float s, c;
  sincosf(f, &s, &c);
  float x1 = q[base], x2 = q[base + 32];
  q[base]      = x1 * c - x2 * s;
  q[base + 32] = x1 * s + x2 * c;
  float y1 = k[base], y2 = k[base + 32];
  k[base]      = y1 * c - y2 * s;
  k[base + 32] = y1 * s + y2 * c;
}

// ---------------------------------------------------------------------------
// Compressed token build: xc[b,w,:] = sum_r softmax(gate)[r] * x[b, 4w+r, :]
// ---------------------------------------------------------------------------
__global__ void xc_kernel(const float* __restrict__ x,
                          const float* __restrict__ gate,
                          float* __restrict__ xc) {
  int idx = blockIdx.x * blockDim.x + threadIdx.x;
  const int total = BATCH * LC * DMODEL;
  if (idx >= total) return;
  int d = idx & 511;
  int w = (idx >> 9) % LC;
  int b = idx / (LC * DMODEL);
  float g[8];
  float m = -1e30f;
#pragma unroll
  for (int r = 0; r < 8; ++r) { g[r] = gate[r]; m = fmaxf(m, g[r]); }
  float ssum = 0.f;
#pragma unroll
  for (int r = 0; r < 8; ++r) { g[r] = __expf(g[r] - m); ssum += g[r]; }
  float inv = 1.f / ssum;
  float acc = 0.f;
  const float* xb = x + ((size_t)b * LSEQ + w * STRIDE) * DMODEL + d;
#pragma unroll
  for (int r = 0; r < 8; ++r) acc += g[r] * xb[(size_t)r * DMODEL];
  xc[idx] = acc * inv;
}

// ---------------------------------------------------------------------------
// Attention: one 64-lane wave per (b,h,p).
// Lane d owns q[d] and out[d]. Scores staged in LDS (<=511 comp + 128 win + 1 sink).
// ---------------------------------------------------------------------------
__device__ inline float wave_sum64(float t) {
  t += __shfl_xor(t, 32); t += __shfl_xor(t, 16); t += __shfl_xor(t, 8);
  t += __shfl_xor(t, 4);  t += __shfl_xor(t, 2);  t += __shfl_xor(t, 1);
  return t;
}
__device__ inline float wave_max64(float t) {
  t = fmaxf(t, __shfl_xor(t, 32)); t = fmaxf(t, __shfl_xor(t, 16));
  t = fmaxf(t, __shfl_xor(t, 8));  t = fmaxf(t, __shfl_xor(t, 4));
  t = fmaxf(t, __shfl_xor(t, 2));  t = fmaxf(t, __shfl_xor(t, 1));
  return t;
}

__global__ __launch_bounds__(64) void attn_kernel(const float* __restrict__ q,
                                                  const float* __restrict__ k,
                                                  const float* __restrict__ v,
                                                  const float* __restrict__ kc,
                                                  const float* __restrict__ vc,
                                                  const float* __restrict__ sink,
                                                  float* __restrict__ o) {
  __shared__ float sc[640];
  const int gid = blockIdx.x;
  const int p = gid & 2047;
  const int h = (gid >> 11) & 7;
  const int b = gid >> 14;
  const int lane = threadIdx.x;

  const size_t qbase = ((size_t)(b * LSEQ + p)) * DMODEL + h * HD + lane;
  const float qv = q[qbase];

  const int nc = (p >= 7) ? (((p - 7) >> 2) + 1) : 0;
  const int k0 = (p > WINDOW - 1) ? (p - (WINDOW - 1)) : 0;
  const int nw = p - k0 + 1;
  const int nt = nc + nw + 1;

  // compressed scores
  for (int c = 0; c < nc; ++c) {
    float t = qv * kc[((size_t)(b * LC + c)) * DMODEL + h * HD + lane];
    t = wave_sum64(t);
    if (lane == 0) sc[c] = t * 0.125f;  // /sqrt(64)
  }
  // window scores
  for (int i = 0; i < nw; ++i) {
    float t = qv * k[((size_t)(b * LSEQ + k0 + i)) * DMODEL + h * HD + lane];
    t = wave_sum64(t);
    if (lane == 0) sc[nc + i] = t * 0.125f;
  }
  if (lane == 0) sc[nc + nw] = sink[h];  // sink logit, unscaled
  __syncthreads();

  // softmax over sc[0..nt)
  float m = -1e30f;
  for (int i = lane; i < nt; i += 64) m = fmaxf(m, sc[i]);
  m = wave_max64(m);
  float ssum = 0.f;
  for (int i = lane; i < nt; i += 64) {
    float e = __expf(sc[i] - m);
    sc[i] = e;
    ssum += e;
  }
  ssum = wave_sum64(ssum);
  __syncthreads();
  const float inv = 1.f / ssum;

  // PV: lane owns dim `lane`
  float acc = 0.f;
  for (int c = 0; c < nc; ++c)
    acc += sc[c] * vc[((size_t)(b * LC + c)) * DMODEL + h * HD + lane];
  for (int i = 0; i < nw; ++i)
    acc += sc[nc + i] * v[((size_t)(b * LSEQ + k0 + i)) * DMODEL + h * HD + lane];

  o[qbase] = acc * inv;
}

// ---------------------------------------------------------------------------
// Launch
// ---------------------------------------------------------------------------
extern "C" void kernel_launch(void* const* d_in, const int* in_sizes, int n_in,
                              void* d_out, int out_size, void* d_ws, size_t ws_size,
                              hipStream_t stream) {
  const float* x    = (const float*)d_in[0];
  const float* wq   = (const float*)d_in[1];
  const float* wk   = (const float*)d_in[2];
  const float* wv   = (const float*)d_in[3];
  const float* wo   = (const float*)d_in[4];
  const float* wkc  = (const float*)d_in[5];
  const float* wvc  = (const float*)d_in[6];
  const float* gate = (const float*)d_in[7];
  const float* sink = (const float*)d_in[8];
  float* out = (float*)d_out;

  const int BL = BATCH * LSEQ;      // 4096
  const int BLC = BATCH * LC;       // 1022

  float* ws = (float*)d_ws;
  float* q  = ws;
  float* k  = q + (size_t)BL * DMODEL;
  float* v  = k + (size_t)BL * DMODEL;
  float* o  = v + (size_t)BL * DMODEL;
  float* xc = o + (size_t)BL * DMODEL;
  float* kc = xc + (size_t)BLC * DMODEL;
  float* vc = kc + (size_t)BLC * DMODEL;

  dim3 blk(256);
  dim3 gBig((BL + 63) / 64, DMODEL / 64);    // 64 x 8
  dim3 gCmp((BLC + 63) / 64, DMODEL / 64);   // 16 x 8

  gemm_bt_f32<<<gBig, blk, 0, stream>>>(x, wq, q, BL, DMODEL, DMODEL);
  gemm_bt_f32<<<gBig, blk, 0, stream>>>(x, wk, k, BL, DMODEL, DMODEL);
  gemm_bt_f32<<<gBig, blk, 0, stream>>>(x, wv, v, BL, DMODEL, DMODEL);

  {
    int total = BATCH * LSEQ * NHEADS * 32;
    rope_kernel<<<(total + 255) / 256, 256, 0, stream>>>(q, k);
  }
  {
    int total = BATCH * LC * DMODEL;
    xc_kernel<<<(total + 255) / 256, 256, 0, stream>>>(x, gate, xc);
  }

  gemm_bt_f32<<<gCmp, blk, 0, stream>>>(xc, wkc, kc, BLC, DMODEL, DMODEL);
  gemm_bt_f32<<<gCmp, blk, 0, stream>>>(xc, wvc, vc, BLC, DMODEL, DMODEL);

  attn_kernel<<<BATCH * NHEADS * LSEQ, 64, 0, stream>>>(q, k, v, kc, vc, sink, o);

  gemm_bt_f32<<<gBig, blk, 0, stream>>>(o, wo, out, BL, DMODEL, DMODEL);
}

// Round 2
// 464.781 us; speedup vs baseline: 2.6857x; 2.6857x over previous
//
#include <hip/hip_runtime.h>
#include <hip/hip_bf16.h>
#include <cmath>

// Problem constants
#define BATCH 2
#define LSEQ 2048
#define DMODEL 512
#define NHEADS 8
#define HD 64
#define RATIO 8
#define STRIDE 4
#define WINDOW 128
#define LC 511   // (2048-8)/4 + 1

// ---------------------------------------------------------------------------
// Generic fp32 GEMM: C[M,N] = A[M,K] * B[N,K]^T   (both row-major)
// 64x64 tile, 256 threads, 4x4 per thread, BK=16.
// ---------------------------------------------------------------------------
__global__ __launch_bounds__(256) void gemm_bt_f32(const float* __restrict__ A,
                                                   const float* __restrict__ B,
                                                   float* __restrict__ C,
                                                   int M, int N, int K) {
  __shared__ float As[16][64];
  __shared__ float Bs[16][64];
  const int tid = threadIdx.x;
  const int tx = tid & 15;
  const int ty = tid >> 4;
  const int bm = blockIdx.x * 64;
  const int bn = blockIdx.y * 64;
  const int lrow = tid >> 2;
  const int lk = (tid & 3) * 4;
  float acc[4][4] = {{0.f}};
  const int arow = bm + lrow;
  const int brow = bn + lrow;
  for (int k0 = 0; k0 < K; k0 += 16) {
    float4 a4 = make_float4(0.f, 0.f, 0.f, 0.f);
    float4 b4 = make_float4(0.f, 0.f, 0.f, 0.f);
    if (arow < M) a4 = *(const float4*)(A + (size_t)arow * K + k0 + lk);
    b4 = *(const float4*)(B + (size_t)brow * K + k0 + lk);
    As[lk + 0][lrow] = a4.x; As[lk + 1][lrow] = a4.y;
    As[lk + 2][lrow] = a4.z; As[lk + 3][lrow] = a4.w;
    Bs[lk + 0][lrow] = b4.x; Bs[lk + 1][lrow] = b4.y;
    Bs[lk + 2][lrow] = b4.z; Bs[lk + 3][lrow] = b4.w;
    __syncthreads();
#pragma unroll
    for (int kk = 0; kk < 16; ++kk) {
      const float4 av = *(const float4*)&As[kk][ty * 4];
      const float4 bv = *(const float4*)&Bs[kk][tx * 4];
      float a[4] = {av.x, av.y, av.z, av.w};
      float b[4] = {bv.x, bv.y, bv.z, bv.w};
#pragma unroll
      for (int i = 0; i < 4; ++i)
#pragma unroll
        for (int j = 0; j < 4; ++j) acc[i][j] += a[i] * b[j];
    }
    __syncthreads();
  }
#pragma unroll
  for (int i = 0; i < 4; ++i) {
    int row = bm + ty * 4 + i;
    if (row < M) {
#pragma unroll
      for (int j = 0; j < 4; ++j)
        C[(size_t)row * N + bn + tx * 4 + j] = acc[i][j];
    }
  }
}

// ---------------------------------------------------------------------------
// RoPE in-place on q and k.
// ---------------------------------------------------------------------------
__global__ void rope_kernel(float* __restrict__ q, float* __restrict__ k) {
  int idx = blockIdx.x * blockDim.x + threadIdx.x;
  const int total = BATCH * LSEQ * NHEADS * 32;
  if (idx >= total) return;
  int j = idx & 31;
  int h = (idx >> 5) & 7;
  int p = (idx >> 8) & 2047;
  int b = idx >> 19;
  size_t base = ((size_t)(b * LSEQ + p)) * DMODEL + h * HD + j;
  float inv_freq = expf(-(float)j * (9.210340371976184f / 32.f));
  float f = (float)p * inv_freq;
  float s, c;
  sincosf(f, &s, &c);
  float x1 = q[base], x2 = q[base + 32];
  q[base]      = x1 * c - x2 * s;
  q[base + 32] = x1 * s + x2 * c;
  float y1 = k[base], y2 = k[base + 32];
  k[base]      = y1 * c - y2 * s;
  k[base + 32] = y1 * s + y2 * c;
}

// ---------------------------------------------------------------------------
// Compressed token build
// ---------------------------------------------------------------------------
__global__ void xc_kernel(const float* __restrict__ x,
                          const float* __restrict__ gate,
                          float* __restrict__ xc) {
  int idx = blockIdx.x * blockDim.x + threadIdx.x;
  const int total = BATCH * LC * DMODEL;
  if (idx >= total) return;
  int d = idx & 511;
  int w = (idx >> 9) % LC;
  int b = idx / (LC * DMODEL);
  float g[8];
  float m = -1e30f;
#pragma unroll
  for (int r = 0; r < 8; ++r) { g[r] = gate[r]; m = fmaxf(m, g[r]); }
  float ssum = 0.f;
#pragma unroll
  for (int r = 0; r < 8; ++r) { g[r] = __expf(g[r] - m); ssum += g[r]; }
  float inv = 1.f / ssum;
  float acc = 0.f;
  const float* xb = x + ((size_t)b * LSEQ + w * STRIDE) * DMODEL + d;
#pragma unroll
  for (int r = 0; r < 8; ++r) acc += g[r] * xb[(size_t)r * DMODEL];
  xc[idx] = acc * inv;
}

// ---------------------------------------------------------------------------
// Attention v2: flash-style. Block = (b,h,qtile of 64). 4 waves split keys.
// Thread = one query: Q row + O acc in registers, private online softmax.
// K/V tiles (16 keys) staged into per-wave LDS; broadcast reads.
// ---------------------------------------------------------------------------
__global__ __launch_bounds__(256, 2) void attn_kernel(
    const float* __restrict__ q, const float* __restrict__ k,
    const float* __restrict__ v, const float* __restrict__ kc,
    const float* __restrict__ vc, const float* __restrict__ sink,
    float* __restrict__ o) {
  __shared__ float tileK[4][16][64];
  __shared__ float tileV[4][16][64];
  __shared__ float mlsh[2][4][64];
  __shared__ float Osh[64][65];

  const int qt = blockIdx.x, h = blockIdx.y, b = blockIdx.z;
  const int tid = threadIdx.x;
  const int w = tid >> 6, lane = tid & 63;
  const int q0 = qt * 64;
  const int p = q0 + lane;
  const int hoff = h * HD;

  // Q row into registers
  float4 Qr[16];
  const float* qrow = q + ((size_t)(b * LSEQ + p)) * DMODEL + hoff;
#pragma unroll
  for (int i = 0; i < 16; ++i) Qr[i] = ((const float4*)qrow)[i];

  float4 Ov[16];
#pragma unroll
  for (int i = 0; i < 16; ++i) Ov[i] = make_float4(0.f, 0.f, 0.f, 0.f);
  float m = -3.0e38f, l = 0.f;

  float* myK = &tileK[w][0][0];
  float* myV = &tileV[w][0][0];

  // ======== Phase C: compressed keys [0, ncm) ========
  const int ncm = (q0 >> 2) + 15;          // nc at p = q0+63
  const int ntc = (ncm + 15) >> 4;
  for (int t = w; t < ntc; t += 4) {
    const int c0 = t * 16;
#pragma unroll
    for (int r = 0; r < 4; ++r) {
      int idx = r * 64 + lane;
      int kk = idx >> 4, d4 = idx & 15;
      int c = c0 + kk; if (c > LC - 1) c = LC - 1;
      size_t off = ((size_t)(b * LC + c)) * DMODEL + hoff + d4 * 4;
      *(float4*)&myK[kk * 64 + d4 * 4] = *(const float4*)(kc + off);
      *(float4*)&myV[kk * 64 + d4 * 4] = *(const float4*)(vc + off);
    }
    asm volatile("" ::: "memory");
    float s[16];
#pragma unroll
    for (int kk = 0; kk < 16; ++kk) s[kk] = 0.f;
#pragma unroll
    for (int d4 = 0; d4 < 16; ++d4) {
      float4 qv = Qr[d4];
#pragma unroll
      for (int kk = 0; kk < 16; ++kk) {
        float4 kv = *(const float4*)&myK[kk * 64 + d4 * 4];
        s[kk] += qv.x * kv.x + qv.y * kv.y + qv.z * kv.z + qv.w * kv.w;
      }
    }
    float tmax = -3.0e38f;
#pragma unroll
    for (int kk = 0; kk < 16; ++kk) {
      int c = c0 + kk;
      bool valid = (c < ncm) && (p >= c * STRIDE + RATIO - 1);
      s[kk] = valid ? s[kk] * 0.125f : -3.0e38f;
      tmax = fmaxf(tmax, s[kk]);
    }
    if (tmax > m) {
      float sc = __expf(m - tmax);
      l *= sc;
#pragma unroll
      for (int i = 0; i < 16; ++i) {
        Ov[i].x *= sc; Ov[i].y *= sc; Ov[i].z *= sc; Ov[i].w *= sc;
      }
      m = tmax;
    }
    float e[16];
#pragma unroll
    for (int kk = 0; kk < 16; ++kk) {
      e[kk] = (s[kk] > -1.0e38f) ? __expf(s[kk] - m) : 0.f;
      l += e[kk];
    }
#pragma unroll
    for (int d4 = 0; d4 < 16; ++d4) {
      float4 acc = Ov[d4];
#pragma unroll
      for (int kk = 0; kk < 16; ++kk) {
        float4 vv = *(const float4*)&myV[kk * 64 + d4 * 4];
        acc.x += e[kk] * vv.x; acc.y += e[kk] * vv.y;
        acc.z += e[kk] * vv.z; acc.w += e[kk] * vv.w;
      }
      Ov[d4] = acc;
    }
    asm volatile("" ::: "memory");
  }

  // ======== Phase W: window keys [w0, q0+63] ========
  const int w0 = (q0 > WINDOW - 1) ? (q0 - (WINDOW - 1)) : 0;
  const int nwk = q0 + 63 - w0 + 1;
  const int ntw = (nwk + 15) >> 4;
  for (int t = w; t < ntw; t += 4) {
    const int k0 = w0 + t * 16;
#pragma unroll
    for (int r = 0; r < 4; ++r) {
      int idx = r * 64 + lane;
      int kk = idx >> 4, d4 = idx & 15;
      int pk = k0 + kk; if (pk > LSEQ - 1) pk = LSEQ - 1;
      size_t off = ((size_t)(b * LSEQ + pk)) * DMODEL + hoff + d4 * 4;
      *(float4*)&myK[kk * 64 + d4 * 4] = *(const float4*)(k + off);
      *(float4*)&myV[kk * 64 + d4 * 4] = *(const float4*)(v + off);
    }
    asm volatile("" ::: "memory");
    float s[16];
#pragma unroll
    for (int kk = 0; kk < 16; ++kk) s[kk] = 0.f;
#pragma unroll
    for (int d4 = 0; d4 < 16; ++d4) {
      float4 qv = Qr[d4];
#pragma unroll
      for (int kk = 0; kk < 16; ++kk) {
        float4 kv = *(const float4*)&myK[kk * 64 + d4 * 4];
        s[kk] += qv.x * kv.x + qv.y * kv.y + qv.z * kv.z + qv.w * kv.w;
      }
    }
    float tmax = -3.0e38f;
#pragma unroll
    for (int kk = 0; kk < 16; ++kk) {
      int pk = k0 + kk;
      bool valid = (p >= pk) && (p - pk < WINDOW);
      s[kk] = valid ? s[kk] * 0.125f : -3.0e38f;
      tmax = fmaxf(tmax, s[kk]);
    }
    if (tmax > m) {
      float sc = __expf(m - tmax);
      l *= sc;
#pragma unroll
      for (int i = 0; i < 16; ++i) {
        Ov[i].x *= sc; Ov[i].y *= sc; Ov[i].z *= sc; Ov[i].w *= sc;
      }
      m = tmax;
    }
    float e[16];
#pragma unroll
    for (int kk = 0; kk < 16; ++kk) {
      e[kk] = (s[kk] > -1.0e38f) ? __expf(s[kk] - m) : 0.f;
      l += e[kk];
    }
#pragma unroll
    for (int d4 = 0; d4 < 16; ++d4) {
      float4 acc = Ov[d4];
#pragma unroll
      for (int kk = 0; kk < 16; ++kk) {
        float4 vv = *(const float4*)&myV[kk * 64 + d4 * 4];
        acc.x += e[kk] * vv.x; acc.y += e[kk] * vv.y;
        acc.z += e[kk] * vv.z; acc.w += e[kk] * vv.w;
      }
      Ov[d4] = acc;
    }
    asm volatile("" ::: "memory");
  }

  // ======== Merge across the 4 waves ========
  mlsh[0][w][lane] = m;
  mlsh[1][w][lane] = l;
  __syncthreads();
  float ms = -3.0e38f;
#pragma unroll
  for (int ww = 0; ww < 4; ++ww) ms = fmaxf(ms, mlsh[0][ww][lane]);
  const float snk = sink[h];
  ms = fmaxf(ms, snk);
  float ls = __expf(snk - ms);  // sink contributes to denominator only
#pragma unroll
  for (int ww = 0; ww < 4; ++ww)
    ls += mlsh[1][ww][lane] * __expf(mlsh[0][ww][lane] - ms);
  const float myscale = __expf(m - ms) / ls;

  for (int ww = 0; ww < 4; ++ww) {
    if (w == ww) {
      if (ww == 0) {
#pragma unroll
        for (int d4 = 0; d4 < 16; ++d4) {
          Osh[lane][d4 * 4 + 0] = myscale * Ov[d4].x;
          Osh[lane][d4 * 4 + 1] = myscale * Ov[d4].y;
          Osh[lane][d4 * 4 + 2] = myscale * Ov[d4].z;
          Osh[lane][d4 * 4 + 3] = myscale * Ov[d4].w;
        }
      } else {
#pragma unroll
        for (int d4 = 0; d4 < 16; ++d4) {
          Osh[lane][d4 * 4 + 0] += myscale * Ov[d4].x;
          Osh[lane][d4 * 4 + 1] += myscale * Ov[d4].y;
          Osh[lane][d4 * 4 + 2] += myscale * Ov[d4].z;
          Osh[lane][d4 * 4 + 3] += myscale * Ov[d4].w;
        }
      }
    }
    __syncthreads();
  }

  // write out: wave w handles rows [w*16, w*16+16)
#pragma unroll
  for (int r = 0; r < 16; ++r) {
    int row = w * 16 + r;
    o[((size_t)(b * LSEQ + q0 + row)) * DMODEL + hoff + lane] = Osh[row][lane];
  }
}

// ---------------------------------------------------------------------------
// Launch
// ---------------------------------------------------------------------------
extern "C" void kernel_launch(void* const* d_in, const int* in_sizes, int n_in,
                              void* d_out, int out_size, void* d_ws, size_t ws_size,
                              hipStream_t stream) {
  const float* x    = (const float*)d_in[0];
  const float* wq   = (const float*)d_in[1];
  const float* wk   = (const float*)d_in[2];
  const float* wv   = (const float*)d_in[3];
  const float* wo   = (const float*)d_in[4];
  const float* wkc  = (const float*)d_in[5];
  const float* wvc  = (const float*)d_in[6];
  const float* gate = (const float*)d_in[7];
  const float* sink = (const float*)d_in[8];
  float* out = (float*)d_out;

  const int BL = BATCH * LSEQ;      // 4096
  const int BLC = BATCH * LC;       // 1022

  float* ws = (float*)d_ws;
  float* q  = ws;
  float* k  = q + (size_t)BL * DMODEL;
  float* v  = k + (size_t)BL * DMODEL;
  float* o  = v + (size_t)BL * DMODEL;
  float* xc = o + (size_t)BL * DMODEL;
  float* kc = xc + (size_t)BLC * DMODEL;
  float* vc = kc + (size_t)BLC * DMODEL;

  dim3 blk(256);
  dim3 gBig((BL + 63) / 64, DMODEL / 64);
  dim3 gCmp((BLC + 63) / 64, DMODEL / 64);

  gemm_bt_f32<<<gBig, blk, 0, stream>>>(x, wq, q, BL, DMODEL, DMODEL);
  gemm_bt_f32<<<gBig, blk, 0, stream>>>(x, wk, k, BL, DMODEL, DMODEL);
  gemm_bt_f32<<<gBig, blk, 0, stream>>>(x, wv, v, BL, DMODEL, DMODEL);

  {
    int total = BATCH * LSEQ * NHEADS * 32;
    rope_kernel<<<(total + 255) / 256, 256, 0, stream>>>(q, k);
  }
  {
    int total = BATCH * LC * DMODEL;
    xc_kernel<<<(total + 255) / 256, 256, 0, stream>>>(x, gate, xc);
  }

  gemm_bt_f32<<<gCmp, blk, 0, stream>>>(xc, wkc, kc, BLC, DMODEL, DMODEL);
  gemm_bt_f32<<<gCmp, blk, 0, stream>>>(xc, wvc, vc, BLC, DMODEL, DMODEL);

  attn_kernel<<<dim3(LSEQ / 64, NHEADS, BATCH), 256, 0, stream>>>(
      q, k, v, kc, vc, sink, o);

  gemm_bt_f32<<<gBig, blk, 0, stream>>>(o, wo, out, BL, DMODEL, DMODEL);
}

// Round 3
// 269.758 us; speedup vs baseline: 4.6274x; 1.7230x over previous
//
#include <hip/hip_runtime.h>
#include <hip/hip_bf16.h>
#include <cmath>

#define BATCH 2
#define LSEQ 2048
#define DMODEL 512
#define NHEADS 8
#define HD 64
#define RATIO 8
#define STRIDE 4
#define WINDOW 128
#define LC 511   // (2048-8)/4 + 1

typedef short short8 __attribute__((ext_vector_type(8)));
typedef float floatx4 __attribute__((ext_vector_type(4)));

__device__ inline unsigned short f2bf(float f) {
  unsigned u = __float_as_uint(f);
  u += 0x7FFFu + ((u >> 16) & 1u);
  return (unsigned short)(u >> 16);
}

// ---------------------------------------------------------------------------
// fp32 -> bf16 conversion (vectorized: float4 -> 4x bf16)
// ---------------------------------------------------------------------------
__global__ void conv_f2bf(const float* __restrict__ src,
                          unsigned short* __restrict__ dst, int n4) {
  int i = blockIdx.x * blockDim.x + threadIdx.x;
  if (i >= n4) return;
  float4 v = ((const float4*)src)[i];
  ushort4 o;
  o.x = f2bf(v.x); o.y = f2bf(v.y); o.z = f2bf(v.z); o.w = f2bf(v.w);
  ((ushort4*)dst)[i] = o;
}

// ---------------------------------------------------------------------------
// bf16 MFMA GEMM: C[M,N] = A[M,K] * B[N,K]^T, A/B bf16 row-major, C = OutT.
// 64x64 tile, BK=64, 4 waves, each wave a 32x32 quadrant (2x2 16x16 frags).
// LDS rows padded to 72 bf16 (144 B) -> 16B-aligned rows, uniform bank use.
// ---------------------------------------------------------------------------
template <typename OutT>
__global__ __launch_bounds__(256) void gemm_bt_mfma(
    const unsigned short* __restrict__ A, const unsigned short* __restrict__ B,
    OutT* __restrict__ C, int M, int N, int K) {
  __shared__ short As[64][72];
  __shared__ short Bs[64][72];
  const int tid = threadIdx.x;
  const int w = tid >> 6, l = tid & 63;
  const int bm = blockIdx.x * 64, bn = blockIdx.y * 64;
  const int wm = (w >> 1) * 32, wn = (w & 1) * 32;

  floatx4 acc[2][2];
#pragma unroll
  for (int i = 0; i < 2; ++i)
#pragma unroll
    for (int j = 0; j < 2; ++j) acc[i][j] = 0.f;

  // staging: chunk c in [0,512): row=c>>3, col8=(c&7)*8 bf16 (16B)
  const int r0 = tid >> 3, c0 = (tid & 7) * 8;
  const int r1 = r0 + 32;

  int ar0 = bm + r0; if (ar0 >= M) ar0 = M - 1;
  int ar1 = bm + r1; if (ar1 >= M) ar1 = M - 1;
  const int br0 = bn + r0, br1 = bn + r1;

  for (int k0 = 0; k0 < K; k0 += 64) {
    short8 av0 = *(const short8*)(A + (size_t)ar0 * K + k0 + c0);
    short8 av1 = *(const short8*)(A + (size_t)ar1 * K + k0 + c0);
    short8 bv0 = *(const short8*)(B + (size_t)br0 * K + k0 + c0);
    short8 bv1 = *(const short8*)(B + (size_t)br1 * K + k0 + c0);
    __syncthreads();
    *(short8*)&As[r0][c0] = av0;
    *(short8*)&As[r1][c0] = av1;
    *(short8*)&Bs[r0][c0] = bv0;
    *(short8*)&Bs[r1][c0] = bv1;
    __syncthreads();
#pragma unroll
    for (int ks = 0; ks < 2; ++ks) {
      const int kb = ks * 32 + (l >> 4) * 8;
      short8 a0 = *(const short8*)&As[wm + (l & 15)][kb];
      short8 a1 = *(const short8*)&As[wm + 16 + (l & 15)][kb];
      short8 b0 = *(const short8*)&Bs[wn + (l & 15)][kb];
      short8 b1 = *(const short8*)&Bs[wn + 16 + (l & 15)][kb];
      acc[0][0] = __builtin_amdgcn_mfma_f32_16x16x32_bf16(a0, b0, acc[0][0], 0, 0, 0);
      acc[0][1] = __builtin_amdgcn_mfma_f32_16x16x32_bf16(a0, b1, acc[0][1], 0, 0, 0);
      acc[1][0] = __builtin_amdgcn_mfma_f32_16x16x32_bf16(a1, b0, acc[1][0], 0, 0, 0);
      acc[1][1] = __builtin_amdgcn_mfma_f32_16x16x32_bf16(a1, b1, acc[1][1], 0, 0, 0);
    }
  }

  // D layout: col = lane&15, row = (lane>>4)*4 + i  [verified mapping]
#pragma unroll
  for (int mi = 0; mi < 2; ++mi) {
#pragma unroll
    for (int i = 0; i < 4; ++i) {
      int row = bm + wm + mi * 16 + (l >> 4) * 4 + i;
      if (row < M) {
#pragma unroll
        for (int nj = 0; nj < 2; ++nj) {
          int col = bn + wn + nj * 16 + (l & 15);
          float val = acc[mi][nj][i];
          if constexpr (sizeof(OutT) == 2)
            C[(size_t)row * N + col] = (OutT)f2bf(val);
          else
            C[(size_t)row * N + col] = (OutT)val;
        }
      }
    }
  }
}

// ---------------------------------------------------------------------------
// RoPE in-place on fp32 q and k.
// ---------------------------------------------------------------------------
__global__ void rope_kernel(float* __restrict__ q, float* __restrict__ k) {
  int idx = blockIdx.x * blockDim.x + threadIdx.x;
  const int total = BATCH * LSEQ * NHEADS * 32;
  if (idx >= total) return;
  int j = idx & 31;
  int h = (idx >> 5) & 7;
  int p = (idx >> 8) & 2047;
  int b = idx >> 19;
  size_t base = ((size_t)(b * LSEQ + p)) * DMODEL + h * HD + j;
  float inv_freq = expf(-(float)j * (9.210340371976184f / 32.f));
  float f = (float)p * inv_freq;
  float s, c;
  sincosf(f, &s, &c);
  float x1 = q[base], x2 = q[base + 32];
  q[base]      = x1 * c - x2 * s;
  q[base + 32] = x1 * s + x2 * c;
  float y1 = k[base], y2 = k[base + 32];
  k[base]      = y1 * c - y2 * s;
  k[base + 32] = y1 * s + y2 * c;
}

// ---------------------------------------------------------------------------
// Compressed token build: reads fp32 x, writes bf16 xc.
// ---------------------------------------------------------------------------
__global__ void xc_kernel(const float* __restrict__ x,
                          const float* __restrict__ gate,
                          unsigned short* __restrict__ xcb) {
  int idx = blockIdx.x * blockDim.x + threadIdx.x;
  const int total = BATCH * LC * DMODEL;
  if (idx >= total) return;
  int d = idx & 511;
  int w = (idx >> 9) % LC;
  int b = idx / (LC * DMODEL);
  float g[8];
  float m = -1e30f;
#pragma unroll
  for (int r = 0; r < 8; ++r) { g[r] = gate[r]; m = fmaxf(m, g[r]); }
  float ssum = 0.f;
#pragma unroll
  for (int r = 0; r < 8; ++r) { g[r] = __expf(g[r] - m); ssum += g[r]; }
  float inv = 1.f / ssum;
  float acc = 0.f;
  const float* xb = x + ((size_t)b * LSEQ + w * STRIDE) * DMODEL + d;
#pragma unroll
  for (int r = 0; r < 8; ++r) acc += g[r] * xb[(size_t)r * DMODEL];
  xcb[idx] = f2bf(acc * inv);
}

// ---------------------------------------------------------------------------
// Attention v3: flash-style, Q in LDS (XOR-swizzled) -> no register spills.
// Block = (qtile 64, h, b), 4 waves split keys, merge via LDS. Writes bf16 o.
// ---------------------------------------------------------------------------
__global__ __launch_bounds__(256, 1) void attn_kernel(
    const float* __restrict__ q, const float* __restrict__ k,
    const float* __restrict__ v, const float* __restrict__ kc,
    const float* __restrict__ vc, const float* __restrict__ sink,
    unsigned short* __restrict__ ob) {
  __shared__ float pool[8192];     // [0,4096): K tiles, [4096,8192): V tiles
  __shared__ float Qsh[4096];      // 64 rows x 16 float4, col-swizzled
  __shared__ float mlsh[2][4][64];

  const int qt = blockIdx.x, h = blockIdx.y, b = blockIdx.z;
  const int tid = threadIdx.x;
  const int w = tid >> 6, lane = tid & 63;
  const int q0 = qt * 64;
  const int p = q0 + lane;
  const int hoff = h * HD;

  // cooperative swizzled Q-tile load: 64 rows x 16 float4 chunks
  {
    const float* qg = q + ((size_t)(b * LSEQ + q0)) * DMODEL + hoff;
#pragma unroll
    for (int r = 0; r < 4; ++r) {
      int cch = r * 256 + tid;
      int qr = cch >> 4, c4 = cch & 15;
      float4 val = *(const float4*)(qg + (size_t)qr * DMODEL + c4 * 4);
      *(float4*)&Qsh[qr * 64 + ((c4 ^ (qr & 15)) * 4)] = val;
    }
  }
  __syncthreads();

  float4 Ov[16];
#pragma unroll
  for (int i = 0; i < 16; ++i) Ov[i] = make_float4(0.f, 0.f, 0.f, 0.f);
  float m = -3.0e38f, l = 0.f;

  float* myK = pool + w * 1024;
  float* myV = pool + 4096 + w * 1024;

  // ======== Phase C: compressed keys [0, ncm) ========
  const int ncm = (q0 >> 2) + 15;
  const int ntc = (ncm + 15) >> 4;
  for (int t = w; t < ntc; t += 4) {
    const int c0 = t * 16;
#pragma unroll
    for (int r = 0; r < 4; ++r) {
      int idx = r * 64 + lane;
      int kk = idx >> 4, d4 = idx & 15;
      int c = c0 + kk; if (c > LC - 1) c = LC - 1;
      size_t off = ((size_t)(b * LC + c)) * DMODEL + hoff + d4 * 4;
      *(float4*)&myK[kk * 64 + d4 * 4] = *(const float4*)(kc + off);
      *(float4*)&myV[kk * 64 + d4 * 4] = *(const float4*)(vc + off);
    }
    asm volatile("" ::: "memory");
    float s[16];
#pragma unroll
    for (int kk = 0; kk < 16; ++kk) s[kk] = 0.f;
#pragma unroll
    for (int d4 = 0; d4 < 16; ++d4) {
      float4 qv = *(const float4*)&Qsh[lane * 64 + ((d4 ^ (lane & 15)) * 4)];
#pragma unroll
      for (int kk = 0; kk < 16; ++kk) {
        float4 kv = *(const float4*)&myK[kk * 64 + d4 * 4];
        s[kk] += qv.x * kv.x + qv.y * kv.y + qv.z * kv.z + qv.w * kv.w;
      }
    }
    float tmax = -3.0e38f;
#pragma unroll
    for (int kk = 0; kk < 16; ++kk) {
      int c = c0 + kk;
      bool valid = (c < ncm) && (p >= c * STRIDE + RATIO - 1);
      s[kk] = valid ? s[kk] * 0.125f : -3.0e38f;
      tmax = fmaxf(tmax, s[kk]);
    }
    if (tmax > m) {
      float sc = __expf(m - tmax);
      l *= sc;
#pragma unroll
      for (int i = 0; i < 16; ++i) {
        Ov[i].x *= sc; Ov[i].y *= sc; Ov[i].z *= sc; Ov[i].w *= sc;
      }
      m = tmax;
    }
    float e[16];
#pragma unroll
    for (int kk = 0; kk < 16; ++kk) {
      e[kk] = (s[kk] > -1.0e38f) ? __expf(s[kk] - m) : 0.f;
      l += e[kk];
    }
#pragma unroll
    for (int d4 = 0; d4 < 16; ++d4) {
      float4 acc = Ov[d4];
#pragma unroll
      for (int kk = 0; kk < 16; ++kk) {
        float4 vv = *(const float4*)&myV[kk * 64 + d4 * 4];
        acc.x += e[kk] * vv.x; acc.y += e[kk] * vv.y;
        acc.z += e[kk] * vv.z; acc.w += e[kk] * vv.w;
      }
      Ov[d4] = acc;
    }
    asm volatile("" ::: "memory");
  }

  // ======== Phase W: window keys [w0, q0+63] ========
  const int w0 = (q0 > WINDOW - 1) ? (q0 - (WINDOW - 1)) : 0;
  const int nwk = q0 + 63 - w0 + 1;
  const int ntw = (nwk + 15) >> 4;
  for (int t = w; t < ntw; t += 4) {
    const int k0 = w0 + t * 16;
#pragma unroll
    for (int r = 0; r < 4; ++r) {
      int idx = r * 64 + lane;
      int kk = idx >> 4, d4 = idx & 15;
      int pk = k0 + kk; if (pk > LSEQ - 1) pk = LSEQ - 1;
      size_t off = ((size_t)(b * LSEQ + pk)) * DMODEL + hoff + d4 * 4;
      *(float4*)&myK[kk * 64 + d4 * 4] = *(const float4*)(k + off);
      *(float4*)&myV[kk * 64 + d4 * 4] = *(const float4*)(v + off);
    }
    asm volatile("" ::: "memory");
    float s[16];
#pragma unroll
    for (int kk = 0; kk < 16; ++kk) s[kk] = 0.f;
#pragma unroll
    for (int d4 = 0; d4 < 16; ++d4) {
      float4 qv = *(const float4*)&Qsh[lane * 64 + ((d4 ^ (lane & 15)) * 4)];
#pragma unroll
      for (int kk = 0; kk < 16; ++kk) {
        float4 kv = *(const float4*)&myK[kk * 64 + d4 * 4];
        s[kk] += qv.x * kv.x + qv.y * kv.y + qv.z * kv.z + qv.w * kv.w;
      }
    }
    float tmax = -3.0e38f;
#pragma unroll
    for (int kk = 0; kk < 16; ++kk) {
      int pk = k0 + kk;
      bool valid = (p >= pk) && (p - pk < WINDOW);
      s[kk] = valid ? s[kk] * 0.125f : -3.0e38f;
      tmax = fmaxf(tmax, s[kk]);
    }
    if (tmax > m) {
      float sc = __expf(m - tmax);
      l *= sc;
#pragma unroll
      for (int i = 0; i < 16; ++i) {
        Ov[i].x *= sc; Ov[i].y *= sc; Ov[i].z *= sc; Ov[i].w *= sc;
      }
      m = tmax;
    }
    float e[16];
#pragma unroll
    for (int kk = 0; kk < 16; ++kk) {
      e[kk] = (s[kk] > -1.0e38f) ? __expf(s[kk] - m) : 0.f;
      l += e[kk];
    }
#pragma unroll
    for (int d4 = 0; d4 < 16; ++d4) {
      float4 acc = Ov[d4];
#pragma unroll
      for (int kk = 0; kk < 16; ++kk) {
        float4 vv = *(const float4*)&myV[kk * 64 + d4 * 4];
        acc.x += e[kk] * vv.x; acc.y += e[kk] * vv.y;
        acc.z += e[kk] * vv.z; acc.w += e[kk] * vv.w;
      }
      Ov[d4] = acc;
    }
    asm volatile("" ::: "memory");
  }

  // ======== Merge across the 4 waves (Osh overlays K/V pool) ========
  mlsh[0][w][lane] = m;
  mlsh[1][w][lane] = l;
  __syncthreads();
  float ms = -3.0e38f;
#pragma unroll
  for (int ww = 0; ww < 4; ++ww) ms = fmaxf(ms, mlsh[0][ww][lane]);
  const float snk = sink[h];
  ms = fmaxf(ms, snk);
  float ls = __expf(snk - ms);
#pragma unroll
  for (int ww = 0; ww < 4; ++ww)
    ls += mlsh[1][ww][lane] * __expf(mlsh[0][ww][lane] - ms);
  const float myscale = __expf(m - ms) / ls;

  float* Osh = pool;  // 64 x 65 floats = 4160 <= 8192
  for (int ww = 0; ww < 4; ++ww) {
    if (w == ww) {
      if (ww == 0) {
#pragma unroll
        for (int d4 = 0; d4 < 16; ++d4) {
          Osh[lane * 65 + d4 * 4 + 0] = myscale * Ov[d4].x;
          Osh[lane * 65 + d4 * 4 + 1] = myscale * Ov[d4].y;
          Osh[lane * 65 + d4 * 4 + 2] = myscale * Ov[d4].z;
          Osh[lane * 65 + d4 * 4 + 3] = myscale * Ov[d4].w;
        }
      } else {
#pragma unroll
        for (int d4 = 0; d4 < 16; ++d4) {
          Osh[lane * 65 + d4 * 4 + 0] += myscale * Ov[d4].x;
          Osh[lane * 65 + d4 * 4 + 1] += myscale * Ov[d4].y;
          Osh[lane * 65 + d4 * 4 + 2] += myscale * Ov[d4].z;
          Osh[lane * 65 + d4 * 4 + 3] += myscale * Ov[d4].w;
        }
      }
    }
    __syncthreads();
  }

#pragma unroll
  for (int r = 0; r < 16; ++r) {
    int row = w * 16 + r;
    ob[((size_t)(b * LSEQ + q0 + row)) * DMODEL + hoff + lane] =
        f2bf(Osh[row * 65 + lane]);
  }
}

// ---------------------------------------------------------------------------
// Launch
// ---------------------------------------------------------------------------
extern "C" void kernel_launch(void* const* d_in, const int* in_sizes, int n_in,
                              void* d_out, int out_size, void* d_ws, size_t ws_size,
                              hipStream_t stream) {
  const float* x    = (const float*)d_in[0];
  const float* wq   = (const float*)d_in[1];
  const float* wk   = (const float*)d_in[2];
  const float* wv   = (const float*)d_in[3];
  const float* wo   = (const float*)d_in[4];
  const float* wkc  = (const float*)d_in[5];
  const float* wvc  = (const float*)d_in[6];
  const float* gate = (const float*)d_in[7];
  const float* sink = (const float*)d_in[8];
  float* out = (float*)d_out;

  const int BL  = BATCH * LSEQ;   // 4096
  const int BLC = BATCH * LC;     // 1022
  const int NX  = BATCH * LSEQ * DMODEL;   // 2097152
  const int NW  = DMODEL * DMODEL;         // 262144

  // workspace carve (256B-aligned)
  char* wp = (char*)d_ws;
  auto carve = [&](size_t bytes) {
    char* r = wp;
    wp += (bytes + 255) & ~(size_t)255;
    return r;
  };
  float* q  = (float*)carve((size_t)BL * DMODEL * 4);
  float* k  = (float*)carve((size_t)BL * DMODEL * 4);
  float* v  = (float*)carve((size_t)BL * DMODEL * 4);
  float* kc = (float*)carve((size_t)BLC * DMODEL * 4);
  float* vc = (float*)carve((size_t)BLC * DMODEL * 4);
  unsigned short* xb  = (unsigned short*)carve((size_t)NX * 2);
  unsigned short* xcb = (unsigned short*)carve((size_t)BLC * DMODEL * 2);
  unsigned short* ob  = (unsigned short*)carve((size_t)BL * DMODEL * 2);
  unsigned short* wqb  = (unsigned short*)carve((size_t)NW * 2);
  unsigned short* wkb  = (unsigned short*)carve((size_t)NW * 2);
  unsigned short* wvb  = (unsigned short*)carve((size_t)NW * 2);
  unsigned short* wob  = (unsigned short*)carve((size_t)NW * 2);
  unsigned short* wkcb = (unsigned short*)carve((size_t)NW * 2);
  unsigned short* wvcb = (unsigned short*)carve((size_t)NW * 2);

  // conversions
  conv_f2bf<<<(NX / 4 + 255) / 256, 256, 0, stream>>>(x, xb, NX / 4);
  conv_f2bf<<<(NW / 4 + 255) / 256, 256, 0, stream>>>(wq, wqb, NW / 4);
  conv_f2bf<<<(NW / 4 + 255) / 256, 256, 0, stream>>>(wk, wkb, NW / 4);
  conv_f2bf<<<(NW / 4 + 255) / 256, 256, 0, stream>>>(wv, wvb, NW / 4);
  conv_f2bf<<<(NW / 4 + 255) / 256, 256, 0, stream>>>(wo, wob, NW / 4);
  conv_f2bf<<<(NW / 4 + 255) / 256, 256, 0, stream>>>(wkc, wkcb, NW / 4);
  conv_f2bf<<<(NW / 4 + 255) / 256, 256, 0, stream>>>(wvc, wvcb, NW / 4);

  dim3 blk(256);
  dim3 gBig(BL / 64, DMODEL / 64);               // 64 x 8
  dim3 gCmp((BLC + 63) / 64, DMODEL / 64);       // 16 x 8

  gemm_bt_mfma<float><<<gBig, blk, 0, stream>>>(xb, wqb, q, BL, DMODEL, DMODEL);
  gemm_bt_mfma<float><<<gBig, blk, 0, stream>>>(xb, wkb, k, BL, DMODEL, DMODEL);
  gemm_bt_mfma<float><<<gBig, blk, 0, stream>>>(xb, wvb, v, BL, DMODEL, DMODEL);

  {
    int total = BATCH * LSEQ * NHEADS * 32;
    rope_kernel<<<(total + 255) / 256, 256, 0, stream>>>(q, k);
  }
  {
    int total = BATCH * LC * DMODEL;
    xc_kernel<<<(total + 255) / 256, 256, 0, stream>>>(x, gate, xcb);
  }

  gemm_bt_mfma<float><<<gCmp, blk, 0, stream>>>(xcb, wkcb, kc, BLC, DMODEL, DMODEL);
  gemm_bt_mfma<float><<<gCmp, blk, 0, stream>>>(xcb, wvcb, vc, BLC, DMODEL, DMODEL);

  attn_kernel<<<dim3(LSEQ / 64, NHEADS, BATCH), 256, 0, stream>>>(
      q, k, v, kc, vc, sink, ob);

  gemm_bt_mfma<float><<<gBig, blk, 0, stream>>>(ob, wob, out, BL, DMODEL, DMODEL);
}

// Round 4
// 99.001 us; speedup vs baseline: 12.6087x; 2.7248x over previous
//
#include <hip/hip_runtime.h>
#include <hip/hip_bf16.h>
#include <cmath>

#define BATCH 2
#define LSEQ 2048
#define DMODEL 512
#define NHEADS 8
#define HD 64
#define RATIO 8
#define STRIDE 4
#define WINDOW 128
#define LC 511   // (2048-8)/4 + 1

typedef short short8 __attribute__((ext_vector_type(8)));
typedef float floatx4 __attribute__((ext_vector_type(4)));

__device__ inline unsigned short f2bf(float f) {
  unsigned u = __float_as_uint(f);
  u += 0x7FFFu + ((u >> 16) & 1u);
  return (unsigned short)(u >> 16);
}

// ---------------------------------------------------------------------------
// Fused fp32 -> bf16 conversion for x + 6 weight matrices (one launch).
// x: 524288 float4s; each weight: 65536 float4s (2^16).
// ---------------------------------------------------------------------------
__global__ void conv_all(const float* __restrict__ x,
                         const float* __restrict__ w0, const float* __restrict__ w1,
                         const float* __restrict__ w2, const float* __restrict__ w3,
                         const float* __restrict__ w4, const float* __restrict__ w5,
                         unsigned short* __restrict__ xb,
                         unsigned short* __restrict__ d0, unsigned short* __restrict__ d1,
                         unsigned short* __restrict__ d2, unsigned short* __restrict__ d3,
                         unsigned short* __restrict__ d4, unsigned short* __restrict__ d5) {
  int idx = blockIdx.x * blockDim.x + threadIdx.x;
  const float* src;
  unsigned short* dst;
  int off;
  if (idx < 524288) {
    src = x; dst = xb; off = idx;
  } else {
    int r = idx - 524288;
    int wi = r >> 16;
    off = r & 65535;
    switch (wi) {
      case 0: src = w0; dst = d0; break;
      case 1: src = w1; dst = d1; break;
      case 2: src = w2; dst = d2; break;
      case 3: src = w3; dst = d3; break;
      case 4: src = w4; dst = d4; break;
      default: src = w5; dst = d5; break;
    }
  }
  float4 v = ((const float4*)src)[off];
  ushort4 o;
  o.x = f2bf(v.x); o.y = f2bf(v.y); o.z = f2bf(v.z); o.w = f2bf(v.w);
  ((ushort4*)dst)[off] = o;
}

// ---------------------------------------------------------------------------
// bf16 MFMA GEMM: C[M,N] = A[M,K] * B[N,K]^T. 64x64 tile, BK=64, 4 waves.
// ---------------------------------------------------------------------------
template <typename OutT>
__global__ __launch_bounds__(256) void gemm_bt_mfma(
    const unsigned short* __restrict__ A, const unsigned short* __restrict__ B,
    OutT* __restrict__ C, int M, int N, int K) {
  __shared__ short As[64][72];
  __shared__ short Bs[64][72];
  const int tid = threadIdx.x;
  const int w = tid >> 6, l = tid & 63;
  const int bm = blockIdx.x * 64, bn = blockIdx.y * 64;
  const int wm = (w >> 1) * 32, wn = (w & 1) * 32;

  floatx4 acc[2][2];
#pragma unroll
  for (int i = 0; i < 2; ++i)
#pragma unroll
    for (int j = 0; j < 2; ++j) acc[i][j] = 0.f;

  const int r0 = tid >> 3, c0 = (tid & 7) * 8;
  const int r1 = r0 + 32;

  int ar0 = bm + r0; if (ar0 >= M) ar0 = M - 1;
  int ar1 = bm + r1; if (ar1 >= M) ar1 = M - 1;
  const int br0 = bn + r0, br1 = bn + r1;

  for (int k0 = 0; k0 < K; k0 += 64) {
    short8 av0 = *(const short8*)(A + (size_t)ar0 * K + k0 + c0);
    short8 av1 = *(const short8*)(A + (size_t)ar1 * K + k0 + c0);
    short8 bv0 = *(const short8*)(B + (size_t)br0 * K + k0 + c0);
    short8 bv1 = *(const short8*)(B + (size_t)br1 * K + k0 + c0);
    __syncthreads();
    *(short8*)&As[r0][c0] = av0;
    *(short8*)&As[r1][c0] = av1;
    *(short8*)&Bs[r0][c0] = bv0;
    *(short8*)&Bs[r1][c0] = bv1;
    __syncthreads();
#pragma unroll
    for (int ks = 0; ks < 2; ++ks) {
      const int kb = ks * 32 + (l >> 4) * 8;
      short8 a0 = *(const short8*)&As[wm + (l & 15)][kb];
      short8 a1 = *(const short8*)&As[wm + 16 + (l & 15)][kb];
      short8 b0 = *(const short8*)&Bs[wn + (l & 15)][kb];
      short8 b1 = *(const short8*)&Bs[wn + 16 + (l & 15)][kb];
      acc[0][0] = __builtin_amdgcn_mfma_f32_16x16x32_bf16(a0, b0, acc[0][0], 0, 0, 0);
      acc[0][1] = __builtin_amdgcn_mfma_f32_16x16x32_bf16(a0, b1, acc[0][1], 0, 0, 0);
      acc[1][0] = __builtin_amdgcn_mfma_f32_16x16x32_bf16(a1, b0, acc[1][0], 0, 0, 0);
      acc[1][1] = __builtin_amdgcn_mfma_f32_16x16x32_bf16(a1, b1, acc[1][1], 0, 0, 0);
    }
  }

#pragma unroll
  for (int mi = 0; mi < 2; ++mi) {
#pragma unroll
    for (int i = 0; i < 4; ++i) {
      int row = bm + wm + mi * 16 + (l >> 4) * 4 + i;
      if (row < M) {
#pragma unroll
        for (int nj = 0; nj < 2; ++nj) {
          int col = bn + wn + nj * 16 + (l & 15);
          float val = acc[mi][nj][i];
          if constexpr (sizeof(OutT) == 2)
            C[(size_t)row * N + col] = (OutT)f2bf(val);
          else
            C[(size_t)row * N + col] = (OutT)val;
        }
      }
    }
  }
}

// ---------------------------------------------------------------------------
// RoPE: reads fp32 q,k; writes bf16 qb,kb.
// ---------------------------------------------------------------------------
__global__ void rope_kernel(const float* __restrict__ q, const float* __restrict__ k,
                            unsigned short* __restrict__ qb,
                            unsigned short* __restrict__ kb) {
  int idx = blockIdx.x * blockDim.x + threadIdx.x;
  const int total = BATCH * LSEQ * NHEADS * 32;
  if (idx >= total) return;
  int j = idx & 31;
  int h = (idx >> 5) & 7;
  int p = (idx >> 8) & 2047;
  int b = idx >> 19;
  size_t base = ((size_t)(b * LSEQ + p)) * DMODEL + h * HD + j;
  float inv_freq = expf(-(float)j * (9.210340371976184f / 32.f));
  float f = (float)p * inv_freq;
  float s, c;
  sincosf(f, &s, &c);
  float x1 = q[base], x2 = q[base + 32];
  qb[base]      = f2bf(x1 * c - x2 * s);
  qb[base + 32] = f2bf(x1 * s + x2 * c);
  float y1 = k[base], y2 = k[base + 32];
  kb[base]      = f2bf(y1 * c - y2 * s);
  kb[base + 32] = f2bf(y1 * s + y2 * c);
}

// ---------------------------------------------------------------------------
// Compressed token build: reads fp32 x, writes bf16 xc.
// ---------------------------------------------------------------------------
__global__ void xc_kernel(const float* __restrict__ x,
                          const float* __restrict__ gate,
                          unsigned short* __restrict__ xcb) {
  int idx = blockIdx.x * blockDim.x + threadIdx.x;
  const int total = BATCH * LC * DMODEL;
  if (idx >= total) return;
  int d = idx & 511;
  int w = (idx >> 9) % LC;
  int b = idx / (LC * DMODEL);
  float g[8];
  float m = -1e30f;
#pragma unroll
  for (int r = 0; r < 8; ++r) { g[r] = gate[r]; m = fmaxf(m, g[r]); }
  float ssum = 0.f;
#pragma unroll
  for (int r = 0; r < 8; ++r) { g[r] = __expf(g[r] - m); ssum += g[r]; }
  float inv = 1.f / ssum;
  float acc = 0.f;
  const float* xb = x + ((size_t)b * LSEQ + w * STRIDE) * DMODEL + d;
#pragma unroll
  for (int r = 0; r < 8; ++r) acc += g[r] * xb[(size_t)r * DMODEL];
  xcb[idx] = f2bf(acc * inv);
}

// ---------------------------------------------------------------------------
// Attention v4: MFMA flash attention.
// Block = (b,h,qtile 64), 4 waves; wave owns 16 q-rows, iterates all key
// tiles (64 keys each). K staged [64][72] bf16; V staged transposed
// Vt[dim][key]; P transposed through per-wave LDS for the PV MFMA.
// qt reversed for b=1 to balance CU load.
// ---------------------------------------------------------------------------
__global__ __launch_bounds__(256, 4) void attn_kernel(
    const unsigned short* __restrict__ qb, const unsigned short* __restrict__ kb,
    const unsigned short* __restrict__ vb, const unsigned short* __restrict__ kcb,
    const unsigned short* __restrict__ vcb, const float* __restrict__ sink,
    unsigned short* __restrict__ ob) {
  __shared__ short Ks[64][72];
  __shared__ short Vt[64][72];
  __shared__ short Pl[4][16][72];

  const int n = blockIdx.x;
  const int b = n >> 8;
  const int mm = n & 255;
  const int h = mm >> 5;
  int qt = mm & 31;
  if (b) qt = 31 - qt;
  const int q0 = qt * 64;
  const int tid = threadIdx.x;
  const int w = tid >> 6, l = tid & 63;
  const int lr = l & 15, lg = l >> 4;
  const int hoff = h * HD;

  // Q fragments (A-layout): rows q0 + w*16 + lr, k-chunks lg*8 (+0/+32)
  short8 Qa0, Qa1;
  {
    const unsigned short* qrow =
        qb + ((size_t)(b * LSEQ + q0 + w * 16 + lr)) * DMODEL + hoff;
    Qa0 = *(const short8*)(qrow + lg * 8);
    Qa1 = *(const short8*)(qrow + 32 + lg * 8);
  }

  floatx4 Oacc[4];
#pragma unroll
  for (int f = 0; f < 4; ++f) Oacc[f] = 0.f;
  float mrow[4] = {-3.0e38f, -3.0e38f, -3.0e38f, -3.0e38f};
  float lrow[4] = {0.f, 0.f, 0.f, 0.f};

  int ncm = q0 / 4 + 15;
  if (ncm > LC) ncm = LC;
  const int ntc = (ncm + 63) >> 6;
  const int w0 = (q0 > 127) ? (q0 - 127) : 0;
  const int ntw = (q0 + 64 - w0 + 63) >> 6;
  const int ntt = ntc + ntw;

  const int skey = tid >> 2, sd = (tid & 3) * 16;
  const int vkey = (tid & 31) * 2, vd = (tid >> 5) * 8;

  for (int tt = 0; tt < ntt; ++tt) {
    const bool isC = (tt < ntc);
    const int tbase = isC ? tt * 64 : (w0 + (tt - ntc) * 64);
    const unsigned short* Kp = isC ? kcb : kb;
    const unsigned short* Vp = isC ? vcb : vb;
    const int rmax = isC ? (LC - 1) : (LSEQ - 1);
    const size_t brow = isC ? (size_t)(b * LC) : (size_t)(b * LSEQ);

    int kr = tbase + skey;      if (kr > rmax) kr = rmax;
    int vr0 = tbase + vkey;     if (vr0 > rmax) vr0 = rmax;
    int vr1 = tbase + vkey + 1; if (vr1 > rmax) vr1 = rmax;

    __syncthreads();
    {
      const unsigned short* src = Kp + (brow + kr) * DMODEL + hoff + sd;
      short8 k0 = *(const short8*)(src);
      short8 k1 = *(const short8*)(src + 8);
      *(short8*)&Ks[skey][sd] = k0;
      *(short8*)&Ks[skey][sd + 8] = k1;
      short8 v0 = *(const short8*)(Vp + (brow + vr0) * DMODEL + hoff + vd);
      short8 v1 = *(const short8*)(Vp + (brow + vr1) * DMODEL + hoff + vd);
#pragma unroll
      for (int j = 0; j < 8; ++j) {
        unsigned pk = (unsigned)(unsigned short)v0[j] |
                      ((unsigned)(unsigned short)v1[j] << 16);
        *(unsigned*)&Vt[vd + j][vkey] = pk;
      }
    }
    __syncthreads();

    // ---- S = Q K^T ----
    floatx4 S[4];
#pragma unroll
    for (int f = 0; f < 4; ++f) {
      floatx4 acc = 0.f;
      short8 kf0 = *(const short8*)&Ks[f * 16 + lr][lg * 8];
      short8 kf1 = *(const short8*)&Ks[f * 16 + lr][32 + lg * 8];
      acc = __builtin_amdgcn_mfma_f32_16x16x32_bf16(Qa0, kf0, acc, 0, 0, 0);
      acc = __builtin_amdgcn_mfma_f32_16x16x32_bf16(Qa1, kf1, acc, 0, 0, 0);
      S[f] = acc;
    }

    // ---- mask + scale + online softmax ----
    float tmax[4] = {-3.0e38f, -3.0e38f, -3.0e38f, -3.0e38f};
#pragma unroll
    for (int f = 0; f < 4; ++f) {
      const int key = tbase + f * 16 + lr;
#pragma unroll
      for (int i = 0; i < 4; ++i) {
        const int p = q0 + w * 16 + lg * 4 + i;
        bool valid;
        if (isC) valid = (key <= LC - 1) && (p >= key * 4 + 7);
        else     valid = (p >= key) && (p - key < WINDOW);
        float s = valid ? S[f][i] * 0.125f : -3.0e38f;
        S[f][i] = s;
        tmax[i] = fmaxf(tmax[i], s);
      }
    }
#pragma unroll
    for (int i = 0; i < 4; ++i) {
      tmax[i] = fmaxf(tmax[i], __shfl_xor(tmax[i], 1));
      tmax[i] = fmaxf(tmax[i], __shfl_xor(tmax[i], 2));
      tmax[i] = fmaxf(tmax[i], __shfl_xor(tmax[i], 4));
      tmax[i] = fmaxf(tmax[i], __shfl_xor(tmax[i], 8));
    }
    float r[4];
#pragma unroll
    for (int i = 0; i < 4; ++i) {
      float mn = fmaxf(mrow[i], tmax[i]);
      r[i] = __expf(mrow[i] - mn);
      mrow[i] = mn;
    }
#pragma unroll
    for (int f = 0; f < 4; ++f) {
#pragma unroll
      for (int i = 0; i < 4; ++i) Oacc[f][i] *= r[i];
    }
    float lsum[4] = {0.f, 0.f, 0.f, 0.f};
#pragma unroll
    for (int f = 0; f < 4; ++f) {
#pragma unroll
      for (int i = 0; i < 4; ++i) {
        float ee = (S[f][i] > -1.0e38f) ? __expf(S[f][i] - mrow[i]) : 0.f;
        lsum[i] += ee;
        Pl[w][lg * 4 + i][f * 16 + lr] = (short)f2bf(ee);
      }
    }
#pragma unroll
    for (int i = 0; i < 4; ++i) {
      float t = lsum[i];
      t += __shfl_xor(t, 1); t += __shfl_xor(t, 2);
      t += __shfl_xor(t, 4); t += __shfl_xor(t, 8);
      lrow[i] = lrow[i] * r[i] + t;
    }
    asm volatile("s_waitcnt lgkmcnt(0)" ::: "memory");

    // ---- PV ----
#pragma unroll
    for (int c = 0; c < 2; ++c) {
      short8 Pa = *(const short8*)&Pl[w][lr][c * 32 + lg * 8];
#pragma unroll
      for (int f = 0; f < 4; ++f) {
        short8 Vf = *(const short8*)&Vt[f * 16 + lr][c * 32 + lg * 8];
        Oacc[f] = __builtin_amdgcn_mfma_f32_16x16x32_bf16(Pa, Vf, Oacc[f], 0, 0, 0);
      }
    }
  }

  // ---- sink + normalize + write ----
  const float snk = sink[h];
  float osc[4];
#pragma unroll
  for (int i = 0; i < 4; ++i) {
    float ms = fmaxf(mrow[i], snk);
    float sc = __expf(mrow[i] - ms);
    float li = lrow[i] * sc + __expf(snk - ms);
    osc[i] = sc / li;
  }
#pragma unroll
  for (int f = 0; f < 4; ++f) {
#pragma unroll
    for (int i = 0; i < 4; ++i) {
      size_t row = (size_t)(b * LSEQ + q0 + w * 16 + lg * 4 + i);
      ob[row * DMODEL + hoff + f * 16 + lr] = f2bf(Oacc[f][i] * osc[i]);
    }
  }
}

// ---------------------------------------------------------------------------
// Launch
// ---------------------------------------------------------------------------
extern "C" void kernel_launch(void* const* d_in, const int* in_sizes, int n_in,
                              void* d_out, int out_size, void* d_ws, size_t ws_size,
                              hipStream_t stream) {
  const float* x    = (const float*)d_in[0];
  const float* wq   = (const float*)d_in[1];
  const float* wk   = (const float*)d_in[2];
  const float* wv   = (const float*)d_in[3];
  const float* wo   = (const float*)d_in[4];
  const float* wkc  = (const float*)d_in[5];
  const float* wvc  = (const float*)d_in[6];
  const float* gate = (const float*)d_in[7];
  const float* sink = (const float*)d_in[8];
  float* out = (float*)d_out;

  const int BL  = BATCH * LSEQ;   // 4096
  const int BLC = BATCH * LC;     // 1022
  const int NX  = BATCH * LSEQ * DMODEL;   // 2097152
  const int NW  = DMODEL * DMODEL;         // 262144

  char* wp = (char*)d_ws;
  auto carve = [&](size_t bytes) {
    char* r = wp;
    wp += (bytes + 255) & ~(size_t)255;
    return r;
  };
  float* q  = (float*)carve((size_t)BL * DMODEL * 4);
  float* k  = (float*)carve((size_t)BL * DMODEL * 4);
  unsigned short* qbuf = (unsigned short*)carve((size_t)BL * DMODEL * 2);
  unsigned short* kbuf = (unsigned short*)carve((size_t)BL * DMODEL * 2);
  unsigned short* vbuf = (unsigned short*)carve((size_t)BL * DMODEL * 2);
  unsigned short* kcb  = (unsigned short*)carve((size_t)BLC * DMODEL * 2);
  unsigned short* vcb  = (unsigned short*)carve((size_t)BLC * DMODEL * 2);
  unsigned short* xb   = (unsigned short*)carve((size_t)NX * 2);
  unsigned short* xcb  = (unsigned short*)carve((size_t)BLC * DMODEL * 2);
  unsigned short* ob   = (unsigned short*)carve((size_t)BL * DMODEL * 2);
  unsigned short* wqb  = (unsigned short*)carve((size_t)NW * 2);
  unsigned short* wkb  = (unsigned short*)carve((size_t)NW * 2);
  unsigned short* wvb  = (unsigned short*)carve((size_t)NW * 2);
  unsigned short* wob  = (unsigned short*)carve((size_t)NW * 2);
  unsigned short* wkcb = (unsigned short*)carve((size_t)NW * 2);
  unsigned short* wvcb = (unsigned short*)carve((size_t)NW * 2);

  {
    int total4 = NX / 4 + 6 * (NW / 4);   // 524288 + 6*65536
    conv_all<<<(total4 + 255) / 256, 256, 0, stream>>>(
        x, wq, wk, wv, wo, wkc, wvc, xb, wqb, wkb, wvb, wob, wkcb, wvcb);
  }

  dim3 blk(256);
  dim3 gBig(BL / 64, DMODEL / 64);
  dim3 gCmp((BLC + 63) / 64, DMODEL / 64);

  gemm_bt_mfma<float><<<gBig, blk, 0, stream>>>(xb, wqb, q, BL, DMODEL, DMODEL);
  gemm_bt_mfma<float><<<gBig, blk, 0, stream>>>(xb, wkb, k, BL, DMODEL, DMODEL);
  gemm_bt_mfma<unsigned short><<<gBig, blk, 0, stream>>>(xb, wvb, vbuf, BL, DMODEL, DMODEL);

  {
    int total = BATCH * LSEQ * NHEADS * 32;
    rope_kernel<<<(total + 255) / 256, 256, 0, stream>>>(q, k, qbuf, kbuf);
  }
  {
    int total = BATCH * LC * DMODEL;
    xc_kernel<<<(total + 255) / 256, 256, 0, stream>>>(x, gate, xcb);
  }

  gemm_bt_mfma<unsigned short><<<gCmp, blk, 0, stream>>>(xcb, wkcb, kcb, BLC, DMODEL, DMODEL);
  gemm_bt_mfma<unsigned short><<<gCmp, blk, 0, stream>>>(xcb, wvcb, vcb, BLC, DMODEL, DMODEL);

  attn_kernel<<<BATCH * NHEADS * (LSEQ / 64), 256, 0, stream>>>(
      qbuf, kbuf, vbuf, kcb, vcb, sink, ob);

  gemm_bt_mfma<float><<<gBig, blk, 0, stream>>>(ob, wob, out, BL, DMODEL, DMODEL);
}

// Round 5
// 87.020 us; speedup vs baseline: 14.3446x; 1.1377x over previous
//
#include <hip/hip_runtime.h>
#include <hip/hip_bf16.h>
#include <cmath>

#define BATCH 2
#define LSEQ 2048
#define DMODEL 512
#define NHEADS 8
#define HD 64
#define RATIO 8
#define STRIDE 4
#define WINDOW 128
#define LC 511   // (2048-8)/4 + 1

typedef short short8 __attribute__((ext_vector_type(8)));
typedef float floatx4 __attribute__((ext_vector_type(4)));

__device__ inline unsigned short f2bf(float f) {
  unsigned u = __float_as_uint(f);
  u += 0x7FFFu + ((u >> 16) & 1u);
  return (unsigned short)(u >> 16);
}

// async global->LDS 16B (dwordx4). LDS dest must be wave-uniform base;
// HW adds lane*16.
__device__ inline void gld_lds16(const unsigned short* g, short* l) {
  __builtin_amdgcn_global_load_lds(
      (const __attribute__((address_space(1))) unsigned int*)g,
      (__attribute__((address_space(3))) unsigned int*)l, 16, 0, 0);
}

// ---------------------------------------------------------------------------
// Fused elementwise pass: bf16-convert x + 6 weights (into concat buffers)
// + compressed-token build (xc).
// float4/ushort4 granularity. Segments:
//   [0, 524288)            : x -> xb
//   [524288, 917504)       : weights -> wqkvb (0..2), wkvcb (3..4), wob (5)
//   [917504, 1048320)      : xc build (reads x fp32, writes xcb bf16)
// ---------------------------------------------------------------------------
__global__ void conv_all(const float* __restrict__ x,
                         const float* __restrict__ w0, const float* __restrict__ w1,
                         const float* __restrict__ w2, const float* __restrict__ w3,
                         const float* __restrict__ w4, const float* __restrict__ w5,
                         const float* __restrict__ gate,
                         unsigned short* __restrict__ xb,
                         unsigned short* __restrict__ wqkvb,
                         unsigned short* __restrict__ wkvcb,
                         unsigned short* __restrict__ wob,
                         unsigned short* __restrict__ xcb) {
  int idx = blockIdx.x * blockDim.x + threadIdx.x;
  if (idx < 917504) {
    const float* src;
    unsigned short* dst;
    int off;
    if (idx < 524288) {
      src = x; dst = xb; off = idx;
    } else {
      int r = idx - 524288;
      int wi = r >> 16;
      off = r & 65535;
      switch (wi) {
        case 0: src = w0; dst = wqkvb; break;
        case 1: src = w1; dst = wqkvb + 4 * 65536; break;
        case 2: src = w2; dst = wqkvb + 8 * 65536; break;
        case 3: src = w3; dst = wkvcb; break;
        case 4: src = w4; dst = wkvcb + 4 * 65536; break;
        default: src = w5; dst = wob; break;
      }
    }
    float4 v = ((const float4*)src)[off];
    ushort4 o;
    o.x = f2bf(v.x); o.y = f2bf(v.y); o.z = f2bf(v.z); o.w = f2bf(v.w);
    ((ushort4*)dst)[off] = o;
  } else {
    int r = idx - 917504;           // [0, 130816)
    int d4 = r & 127;
    int t = r >> 7;
    int w = t % LC;
    int b = t / LC;
    float g[8];
    float m = -1e30f;
#pragma unroll
    for (int i = 0; i < 8; ++i) { g[i] = gate[i]; m = fmaxf(m, g[i]); }
    float ssum = 0.f;
#pragma unroll
    for (int i = 0; i < 8; ++i) { g[i] = __expf(g[i] - m); ssum += g[i]; }
    float inv = 1.f / ssum;
    const float* xb4 = x + ((size_t)(b * LSEQ + w * STRIDE)) * DMODEL + d4 * 4;
    float4 acc = make_float4(0.f, 0.f, 0.f, 0.f);
#pragma unroll
    for (int i = 0; i < 8; ++i) {
      float4 v = *(const float4*)(xb4 + (size_t)i * DMODEL);
      acc.x += g[i] * v.x; acc.y += g[i] * v.y;
      acc.z += g[i] * v.z; acc.w += g[i] * v.w;
    }
    ushort4 o;
    o.x = f2bf(acc.x * inv); o.y = f2bf(acc.y * inv);
    o.z = f2bf(acc.z * inv); o.w = f2bf(acc.w * inv);
    ((ushort4*)xcb)[(size_t)(b * LC + w) * 128 + d4] = o;
  }
}

// ---------------------------------------------------------------------------
// m97-structure GEMM: C[M,N] = A[M,K] B[N,K]^T, bf16 in, 128x128 tile, BK=64,
// 4 waves (each 64x64 = 4x4 frags of 16x16x32), global_load_lds staging with
// XOR-swizzled source (linear LDS dest, swizzled ds_read -> ~2-way banks).
// MODE 0: QKV split epilogue (col<512 -> C0 fp32, <1024 -> C1 fp32,
//         else C2 bf16, each N=512). MODE 1: plain fp32 C0 (width N).
// ---------------------------------------------------------------------------
template <int MODE>
__global__ __launch_bounds__(256) void gemm128(
    const unsigned short* __restrict__ A, const unsigned short* __restrict__ B,
    float* __restrict__ C0, float* __restrict__ C1,
    unsigned short* __restrict__ C2, int M, int N, int K) {
  __shared__ short As[128 * 64];
  __shared__ short Bs[128 * 64];
  const int tid = threadIdx.x;
  const int w = tid >> 6, l = tid & 63;
  const int lr = l & 15, lg = l >> 4;
  const int bm = blockIdx.x * 128, bn = blockIdx.y * 128;
  const int wm = (w >> 1) * 64, wn = (w & 1) * 64;

  floatx4 acc[4][4];
#pragma unroll
  for (int i = 0; i < 4; ++i)
#pragma unroll
    for (int j = 0; j < 4; ++j) acc[i][j] = 0.f;

  // staging geometry: chunk c = i*256 + tid; row = c>>3 = i*32 + (tid>>3);
  // linear LDS dest; source col16 pre-swizzled: cs = (tid&7) ^ ((tid>>3)&7).
  const int trow = tid >> 3;
  const int cs = (tid & 7) ^ (trow & 7);
  const size_t aoff = (size_t)(bm + trow) * K + cs * 8;
  const size_t boff = (size_t)(bn + trow) * K + cs * 8;
  const int ldsbase = (tid & 192) * 8;   // wave-uniform, in shorts

  for (int k0 = 0; k0 < K; k0 += 64) {
    __syncthreads();   // previous tile fully consumed
#pragma unroll
    for (int i = 0; i < 4; ++i) {
      gld_lds16(A + aoff + (size_t)i * 32 * K + k0, As + i * 2048 + ldsbase);
      gld_lds16(B + boff + (size_t)i * 32 * K + k0, Bs + i * 2048 + ldsbase);
    }
    __syncthreads();   // loads arrived (vmcnt drained by barrier)

#pragma unroll
    for (int kk = 0; kk < 2; ++kk) {
      const int kc16 = kk * 4 + lg;
      short8 a[4], bf[4];
#pragma unroll
      for (int mi = 0; mi < 4; ++mi) {
        int r = wm + mi * 16 + lr;
        a[mi] = *(const short8*)&As[r * 64 + ((kc16 ^ (r & 7)) * 8)];
      }
#pragma unroll
      for (int nj = 0; nj < 4; ++nj) {
        int r = wn + nj * 16 + lr;
        bf[nj] = *(const short8*)&Bs[r * 64 + ((kc16 ^ (r & 7)) * 8)];
      }
#pragma unroll
      for (int mi = 0; mi < 4; ++mi)
#pragma unroll
        for (int nj = 0; nj < 4; ++nj)
          acc[mi][nj] = __builtin_amdgcn_mfma_f32_16x16x32_bf16(
              a[mi], bf[nj], acc[mi][nj], 0, 0, 0);
    }
  }

#pragma unroll
  for (int mi = 0; mi < 4; ++mi) {
#pragma unroll
    for (int i = 0; i < 4; ++i) {
      int row = bm + wm + mi * 16 + lg * 4 + i;
#pragma unroll
      for (int nj = 0; nj < 4; ++nj) {
        int col = bn + wn + nj * 16 + lr;
        float val = acc[mi][nj][i];
        if constexpr (MODE == 0) {
          if (col < 512)       C0[(size_t)row * 512 + col] = val;
          else if (col < 1024) C1[(size_t)row * 512 + col - 512] = val;
          else                 C2[(size_t)row * 512 + col - 1024] = f2bf(val);
        } else {
          C0[(size_t)row * N + col] = val;
        }
      }
    }
  }
}

// ---------------------------------------------------------------------------
// 64x64-tile GEMM with row clamping, split bf16 epilogue (col<512 -> C0,
// else C1). Used for kc/vc (M=1022, N=1024 concat).
// ---------------------------------------------------------------------------
__global__ __launch_bounds__(256) void gemm64_split(
    const unsigned short* __restrict__ A, const unsigned short* __restrict__ B,
    unsigned short* __restrict__ C0, unsigned short* __restrict__ C1,
    int M, int K) {
  __shared__ short As[64][72];
  __shared__ short Bs[64][72];
  const int tid = threadIdx.x;
  const int w = tid >> 6, l = tid & 63;
  const int bm = blockIdx.x * 64, bn = blockIdx.y * 64;
  const int wm = (w >> 1) * 32, wn = (w & 1) * 32;

  floatx4 acc[2][2];
#pragma unroll
  for (int i = 0; i < 2; ++i)
#pragma unroll
    for (int j = 0; j < 2; ++j) acc[i][j] = 0.f;

  const int r0 = tid >> 3, c0 = (tid & 7) * 8;
  const int r1 = r0 + 32;
  int ar0 = bm + r0; if (ar0 >= M) ar0 = M - 1;
  int ar1 = bm + r1; if (ar1 >= M) ar1 = M - 1;
  const int br0 = bn + r0, br1 = bn + r1;

  for (int k0 = 0; k0 < K; k0 += 64) {
    short8 av0 = *(const short8*)(A + (size_t)ar0 * K + k0 + c0);
    short8 av1 = *(const short8*)(A + (size_t)ar1 * K + k0 + c0);
    short8 bv0 = *(const short8*)(B + (size_t)br0 * K + k0 + c0);
    short8 bv1 = *(const short8*)(B + (size_t)br1 * K + k0 + c0);
    __syncthreads();
    *(short8*)&As[r0][c0] = av0;
    *(short8*)&As[r1][c0] = av1;
    *(short8*)&Bs[r0][c0] = bv0;
    *(short8*)&Bs[r1][c0] = bv1;
    __syncthreads();
#pragma unroll
    for (int ks = 0; ks < 2; ++ks) {
      const int kb = ks * 32 + (l >> 4) * 8;
      short8 a0 = *(const short8*)&As[wm + (l & 15)][kb];
      short8 a1 = *(const short8*)&As[wm + 16 + (l & 15)][kb];
      short8 b0 = *(const short8*)&Bs[wn + (l & 15)][kb];
      short8 b1 = *(const short8*)&Bs[wn + 16 + (l & 15)][kb];
      acc[0][0] = __builtin_amdgcn_mfma_f32_16x16x32_bf16(a0, b0, acc[0][0], 0, 0, 0);
      acc[0][1] = __builtin_amdgcn_mfma_f32_16x16x32_bf16(a0, b1, acc[0][1], 0, 0, 0);
      acc[1][0] = __builtin_amdgcn_mfma_f32_16x16x32_bf16(a1, b0, acc[1][0], 0, 0, 0);
      acc[1][1] = __builtin_amdgcn_mfma_f32_16x16x32_bf16(a1, b1, acc[1][1], 0, 0, 0);
    }
  }

#pragma unroll
  for (int mi = 0; mi < 2; ++mi) {
#pragma unroll
    for (int i = 0; i < 4; ++i) {
      int row = bm + wm + mi * 16 + (l >> 4) * 4 + i;
      if (row < M) {
#pragma unroll
        for (int nj = 0; nj < 2; ++nj) {
          int col = bn + wn + nj * 16 + (l & 15);
          unsigned short val = f2bf(acc[mi][nj][i]);
          if (col < 512) C0[(size_t)row * 512 + col] = val;
          else           C1[(size_t)row * 512 + col - 512] = val;
        }
      }
    }
  }
}

// ---------------------------------------------------------------------------
// RoPE: reads fp32 q,k; writes bf16 qb,kb. 2 dims per thread (float2).
// ---------------------------------------------------------------------------
__global__ void rope_kernel(const float* __restrict__ q, const float* __restrict__ k,
                            unsigned short* __restrict__ qb,
                            unsigned short* __restrict__ kb) {
  int idx = blockIdx.x * blockDim.x + threadIdx.x;
  const int total = BATCH * LSEQ * NHEADS * 16;
  if (idx >= total) return;
  int j2 = idx & 15;            // pair of dims: j = j2*2, j2*2+1
  int h = (idx >> 4) & 7;
  int p = (idx >> 7) & 2047;
  int b = idx >> 18;
  size_t base = ((size_t)(b * LSEQ + p)) * DMODEL + h * HD + j2 * 2;
  float j0 = (float)(j2 * 2);
  float if0 = __expf(-j0 * (9.210340371976184f / 32.f));
  float if1 = __expf(-(j0 + 1.f) * (9.210340371976184f / 32.f));
  float s0, c0, s1, c1;
  sincosf((float)p * if0, &s0, &c0);
  sincosf((float)p * if1, &s1, &c1);
  float2 x1 = *(const float2*)(q + base);
  float2 x2 = *(const float2*)(q + base + 32);
  ushort2 o1, o2;
  o1.x = f2bf(x1.x * c0 - x2.x * s0); o1.y = f2bf(x1.y * c1 - x2.y * s1);
  o2.x = f2bf(x1.x * s0 + x2.x * c0); o2.y = f2bf(x1.y * s1 + x2.y * c1);
  *(ushort2*)(qb + base) = o1;
  *(ushort2*)(qb + base + 32) = o2;
  float2 y1 = *(const float2*)(k + base);
  float2 y2 = *(const float2*)(k + base + 32);
  o1.x = f2bf(y1.x * c0 - y2.x * s0); o1.y = f2bf(y1.y * c1 - y2.y * s1);
  o2.x = f2bf(y1.x * s0 + y2.x * c0); o2.y = f2bf(y1.y * s1 + y2.y * c1);
  *(ushort2*)(kb + base) = o1;
  *(ushort2*)(kb + base + 32) = o2;
}

// ---------------------------------------------------------------------------
// Attention v4 (unchanged): MFMA flash attention.
// ---------------------------------------------------------------------------
__global__ __launch_bounds__(256, 4) void attn_kernel(
    const unsigned short* __restrict__ qb, const unsigned short* __restrict__ kb,
    const unsigned short* __restrict__ vb, const unsigned short* __restrict__ kcb,
    const unsigned short* __restrict__ vcb, const float* __restrict__ sink,
    unsigned short* __restrict__ ob) {
  __shared__ short Ks[64][72];
  __shared__ short Vt[64][72];
  __shared__ short Pl[4][16][72];

  const int n = blockIdx.x;
  const int b = n >> 8;
  const int mm = n & 255;
  const int h = mm >> 5;
  int qt = mm & 31;
  if (b) qt = 31 - qt;
  const int q0 = qt * 64;
  const int tid = threadIdx.x;
  const int w = tid >> 6, l = tid & 63;
  const int lr = l & 15, lg = l >> 4;
  const int hoff = h * HD;

  short8 Qa0, Qa1;
  {
    const unsigned short* qrow =
        qb + ((size_t)(b * LSEQ + q0 + w * 16 + lr)) * DMODEL + hoff;
    Qa0 = *(const short8*)(qrow + lg * 8);
    Qa1 = *(const short8*)(qrow + 32 + lg * 8);
  }

  floatx4 Oacc[4];
#pragma unroll
  for (int f = 0; f < 4; ++f) Oacc[f] = 0.f;
  float mrow[4] = {-3.0e38f, -3.0e38f, -3.0e38f, -3.0e38f};
  float lrow[4] = {0.f, 0.f, 0.f, 0.f};

  int ncm = q0 / 4 + 15;
  if (ncm > LC) ncm = LC;
  const int ntc = (ncm + 63) >> 6;
  const int w0 = (q0 > 127) ? (q0 - 127) : 0;
  const int ntw = (q0 + 64 - w0 + 63) >> 6;
  const int ntt = ntc + ntw;

  const int skey = tid >> 2, sd = (tid & 3) * 16;
  const int vkey = (tid & 31) * 2, vd = (tid >> 5) * 8;

  for (int tt = 0; tt < ntt; ++tt) {
    const bool isC = (tt < ntc);
    const int tbase = isC ? tt * 64 : (w0 + (tt - ntc) * 64);
    const unsigned short* Kp = isC ? kcb : kb;
    const unsigned short* Vp = isC ? vcb : vb;
    const int rmax = isC ? (LC - 1) : (LSEQ - 1);
    const size_t brow = isC ? (size_t)(b * LC) : (size_t)(b * LSEQ);

    int kr = tbase + skey;      if (kr > rmax) kr = rmax;
    int vr0 = tbase + vkey;     if (vr0 > rmax) vr0 = rmax;
    int vr1 = tbase + vkey + 1; if (vr1 > rmax) vr1 = rmax;

    __syncthreads();
    {
      const unsigned short* src = Kp + (brow + kr) * DMODEL + hoff + sd;
      short8 k0 = *(const short8*)(src);
      short8 k1 = *(const short8*)(src + 8);
      *(short8*)&Ks[skey][sd] = k0;
      *(short8*)&Ks[skey][sd + 8] = k1;
      short8 v0 = *(const short8*)(Vp + (brow + vr0) * DMODEL + hoff + vd);
      short8 v1 = *(const short8*)(Vp + (brow + vr1) * DMODEL + hoff + vd);
#pragma unroll
      for (int j = 0; j < 8; ++j) {
        unsigned pk = (unsigned)(unsigned short)v0[j] |
                      ((unsigned)(unsigned short)v1[j] << 16);
        *(unsigned*)&Vt[vd + j][vkey] = pk;
      }
    }
    __syncthreads();

    floatx4 S[4];
#pragma unroll
    for (int f = 0; f < 4; ++f) {
      floatx4 acc = 0.f;
      short8 kf0 = *(const short8*)&Ks[f * 16 + lr][lg * 8];
      short8 kf1 = *(const short8*)&Ks[f * 16 + lr][32 + lg * 8];
      acc = __builtin_amdgcn_mfma_f32_16x16x32_bf16(Qa0, kf0, acc, 0, 0, 0);
      acc = __builtin_amdgcn_mfma_f32_16x16x32_bf16(Qa1, kf1, acc, 0, 0, 0);
      S[f] = acc;
    }

    float tmax[4] = {-3.0e38f, -3.0e38f, -3.0e38f, -3.0e38f};
#pragma unroll
    for (int f = 0; f < 4; ++f) {
      const int key = tbase + f * 16 + lr;
#pragma unroll
      for (int i = 0; i < 4; ++i) {
        const int p = q0 + w * 16 + lg * 4 + i;
        bool valid;
        if (isC) valid = (key <= LC - 1) && (p >= key * 4 + 7);
        else     valid = (p >= key) && (p - key < WINDOW);
        float s = valid ? S[f][i] * 0.125f : -3.0e38f;
        S[f][i] = s;
        tmax[i] = fmaxf(tmax[i], s);
      }
    }
#pragma unroll
    for (int i = 0; i < 4; ++i) {
      tmax[i] = fmaxf(tmax[i], __shfl_xor(tmax[i], 1));
      tmax[i] = fmaxf(tmax[i], __shfl_xor(tmax[i], 2));
      tmax[i] = fmaxf(tmax[i], __shfl_xor(tmax[i], 4));
      tmax[i] = fmaxf(tmax[i], __shfl_xor(tmax[i], 8));
    }
    float r[4];
#pragma unroll
    for (int i = 0; i < 4; ++i) {
      float mn = fmaxf(mrow[i], tmax[i]);
      r[i] = __expf(mrow[i] - mn);
      mrow[i] = mn;
    }
#pragma unroll
    for (int f = 0; f < 4; ++f) {
#pragma unroll
      for (int i = 0; i < 4; ++i) Oacc[f][i] *= r[i];
    }
    float lsum[4] = {0.f, 0.f, 0.f, 0.f};
#pragma unroll
    for (int f = 0; f < 4; ++f) {
#pragma unroll
      for (int i = 0; i < 4; ++i) {
        float ee = (S[f][i] > -1.0e38f) ? __expf(S[f][i] - mrow[i]) : 0.f;
        lsum[i] += ee;
        Pl[w][lg * 4 + i][f * 16 + lr] = (short)f2bf(ee);
      }
    }
#pragma unroll
    for (int i = 0; i < 4; ++i) {
      float t = lsum[i];
      t += __shfl_xor(t, 1); t += __shfl_xor(t, 2);
      t += __shfl_xor(t, 4); t += __shfl_xor(t, 8);
      lrow[i] = lrow[i] * r[i] + t;
    }
    asm volatile("s_waitcnt lgkmcnt(0)" ::: "memory");

#pragma unroll
    for (int c = 0; c < 2; ++c) {
      short8 Pa = *(const short8*)&Pl[w][lr][c * 32 + lg * 8];
#pragma unroll
      for (int f = 0; f < 4; ++f) {
        short8 Vf = *(const short8*)&Vt[f * 16 + lr][c * 32 + lg * 8];
        Oacc[f] = __builtin_amdgcn_mfma_f32_16x16x32_bf16(Pa, Vf, Oacc[f], 0, 0, 0);
      }
    }
  }

  const float snk = sink[h];
  float osc[4];
#pragma unroll
  for (int i = 0; i < 4; ++i) {
    float ms = fmaxf(mrow[i], snk);
    float sc = __expf(mrow[i] - ms);
    float li = lrow[i] * sc + __expf(snk - ms);
    osc[i] = sc / li;
  }
#pragma unroll
  for (int f = 0; f < 4; ++f) {
#pragma unroll
    for (int i = 0; i < 4; ++i) {
      size_t row = (size_t)(b * LSEQ + q0 + w * 16 + lg * 4 + i);
      ob[row * DMODEL + hoff + f * 16 + lr] = f2bf(Oacc[f][i] * osc[i]);
    }
  }
}

// ---------------------------------------------------------------------------
// Launch
// ---------------------------------------------------------------------------
extern "C" void kernel_launch(void* const* d_in, const int* in_sizes, int n_in,
                              void* d_out, int out_size, void* d_ws, size_t ws_size,
                              hipStream_t stream) {
  const float* x    = (const float*)d_in[0];
  const float* wq   = (const float*)d_in[1];
  const float* wk   = (const float*)d_in[2];
  const float* wv   = (const float*)d_in[3];
  const float* wo   = (const float*)d_in[4];
  const float* wkc  = (const float*)d_in[5];
  const float* wvc  = (const float*)d_in[6];
  const float* gate = (const float*)d_in[7];
  const float* sink = (const float*)d_in[8];
  float* out = (float*)d_out;

  const int BL  = BATCH * LSEQ;   // 4096
  const int BLC = BATCH * LC;     // 1022
  const int NX  = BATCH * LSEQ * DMODEL;   // 2097152
  const int NW  = DMODEL * DMODEL;         // 262144

  char* wp = (char*)d_ws;
  auto carve = [&](size_t bytes) {
    char* r = wp;
    wp += (bytes + 255) & ~(size_t)255;
    return r;
  };
  float* q  = (float*)carve((size_t)BL * DMODEL * 4);
  float* k  = (float*)carve((size_t)BL * DMODEL * 4);
  unsigned short* qbuf = (unsigned short*)carve((size_t)BL * DMODEL * 2);
  unsigned short* kbuf = (unsigned short*)carve((size_t)BL * DMODEL * 2);
  unsigned short* vbuf = (unsigned short*)carve((size_t)BL * DMODEL * 2);
  unsigned short* kcb  = (unsigned short*)carve((size_t)BLC * DMODEL * 2);
  unsigned short* vcb  = (unsigned short*)carve((size_t)BLC * DMODEL * 2);
  unsigned short* xb   = (unsigned short*)carve((size_t)NX * 2);
  unsigned short* xcb  = (unsigned short*)carve((size_t)BLC * DMODEL * 2);
  unsigned short* ob   = (unsigned short*)carve((size_t)BL * DMODEL * 2);
  unsigned short* wqkvb = (unsigned short*)carve((size_t)NW * 3 * 2);  // [wq;wk;wv]
  unsigned short* wkvcb = (unsigned short*)carve((size_t)NW * 2 * 2);  // [wkc;wvc]
  unsigned short* wob   = (unsigned short*)carve((size_t)NW * 2);

  // 1) fused conversions + xc build
  conv_all<<<4095, 256, 0, stream>>>(x, wq, wk, wv, wkc, wvc, wo, gate,
                                     xb, wqkvb, wkvcb, wob, xcb);

  // 2) fused QKV projection: [4096,512] x [1536,512]^T
  gemm128<0><<<dim3(BL / 128, 1536 / 128), 256, 0, stream>>>(
      xb, wqkvb, q, k, vbuf, BL, 1536, DMODEL);

  // 3) RoPE -> bf16 q,k
  {
    int total = BATCH * LSEQ * NHEADS * 16;
    rope_kernel<<<(total + 255) / 256, 256, 0, stream>>>(q, k, qbuf, kbuf);
  }

  // 4) fused kc/vc: [1022,512] x [1024,512]^T
  gemm64_split<<<dim3((BLC + 63) / 64, 1024 / 64), 256, 0, stream>>>(
      xcb, wkvcb, kcb, vcb, BLC, DMODEL);

  // 5) attention
  attn_kernel<<<BATCH * NHEADS * (LSEQ / 64), 256, 0, stream>>>(
      qbuf, kbuf, vbuf, kcb, vcb, sink, ob);

  // 6) output projection
  gemm128<1><<<dim3(BL / 128, DMODEL / 128), 256, 0, stream>>>(
      ob, wob, out, nullptr, nullptr, BL, DMODEL, DMODEL);
}

// Round 6
// 62.118 us; speedup vs baseline: 20.0953x; 1.4009x over previous
//
#include <hip/hip_runtime.h>
#include <hip/hip_bf16.h>
#include <cmath>

#define BATCH 2
#define LSEQ 2048
#define DMODEL 512
#define NHEADS 8
#define HD 64
#define RATIO 8
#define STRIDE 4
#define WINDOW 128
#define LC 511   // (2048-8)/4 + 1

typedef short short8 __attribute__((ext_vector_type(8)));
typedef float floatx4 __attribute__((ext_vector_type(4)));

__device__ inline unsigned short f2bf(float f) {
  unsigned u = __float_as_uint(f);
  u += 0x7FFFu + ((u >> 16) & 1u);
  return (unsigned short)(u >> 16);
}

// async global->LDS 16B (dwordx4). LDS dest is wave-uniform base + lane*16.
__device__ inline void gld_lds16(const unsigned short* g, short* l) {
  __builtin_amdgcn_global_load_lds(
      (const __attribute__((address_space(1))) unsigned int*)g,
      (__attribute__((address_space(3))) unsigned int*)l, 16, 0, 0);
}

// ---------------------------------------------------------------------------
// Fused elementwise pass:
//   [0, 524288)           : x -> xb (bf16)
//   [524288, 917504)      : 6 weights -> wqkvb/wkvcb/wob (bf16)
//   [917504, 1048320)     : xc build (fp32 x -> bf16 xcb)
//   [1048320, 1113856)    : RoPE cos/sin table (float2 cstab[2048*32])
// ---------------------------------------------------------------------------
__global__ void conv_all(const float* __restrict__ x,
                         const float* __restrict__ w0, const float* __restrict__ w1,
                         const float* __restrict__ w2, const float* __restrict__ w3,
                         const float* __restrict__ w4, const float* __restrict__ w5,
                         const float* __restrict__ gate,
                         unsigned short* __restrict__ xb,
                         unsigned short* __restrict__ wqkvb,
                         unsigned short* __restrict__ wkvcb,
                         unsigned short* __restrict__ wob,
                         unsigned short* __restrict__ xcb,
                         float2* __restrict__ cstab) {
  int idx = blockIdx.x * blockDim.x + threadIdx.x;
  if (idx < 917504) {
    const float* src;
    unsigned short* dst;
    int off;
    if (idx < 524288) {
      src = x; dst = xb; off = idx;
    } else {
      int r = idx - 524288;
      int wi = r >> 16;
      off = r & 65535;
      switch (wi) {
        case 0: src = w0; dst = wqkvb; break;
        case 1: src = w1; dst = wqkvb + 4 * 65536; break;
        case 2: src = w2; dst = wqkvb + 8 * 65536; break;
        case 3: src = w3; dst = wkvcb; break;
        case 4: src = w4; dst = wkvcb + 4 * 65536; break;
        default: src = w5; dst = wob; break;
      }
    }
    float4 v = ((const float4*)src)[off];
    ushort4 o;
    o.x = f2bf(v.x); o.y = f2bf(v.y); o.z = f2bf(v.z); o.w = f2bf(v.w);
    ((ushort4*)dst)[off] = o;
  } else if (idx < 1048320) {
    int r = idx - 917504;           // [0, 130816) = 1022 * 128
    int d4 = r & 127;
    int t = r >> 7;
    int w = t % LC;
    int b = t / LC;
    float g[8];
    float m = -1e30f;
#pragma unroll
    for (int i = 0; i < 8; ++i) { g[i] = gate[i]; m = fmaxf(m, g[i]); }
    float ssum = 0.f;
#pragma unroll
    for (int i = 0; i < 8; ++i) { g[i] = __expf(g[i] - m); ssum += g[i]; }
    float inv = 1.f / ssum;
    const float* xb4 = x + ((size_t)(b * LSEQ + w * STRIDE)) * DMODEL + d4 * 4;
    float4 acc = make_float4(0.f, 0.f, 0.f, 0.f);
#pragma unroll
    for (int i = 0; i < 8; ++i) {
      float4 v = *(const float4*)(xb4 + (size_t)i * DMODEL);
      acc.x += g[i] * v.x; acc.y += g[i] * v.y;
      acc.z += g[i] * v.z; acc.w += g[i] * v.w;
    }
    ushort4 o;
    o.x = f2bf(acc.x * inv); o.y = f2bf(acc.y * inv);
    o.z = f2bf(acc.z * inv); o.w = f2bf(acc.w * inv);
    ((ushort4*)xcb)[(size_t)(b * LC + w) * 128 + d4] = o;
  } else {
    int e = idx - 1048320;          // [0, 65536) = 2048 * 32
    int p = e >> 5, j = e & 31;
    float inv_freq = __expf(-(float)j * (9.210340371976184f / 32.f));
    float s, c;
    sincosf((float)p * inv_freq, &s, &c);
    cstab[e] = make_float2(c, s);
  }
}

// ---------------------------------------------------------------------------
// Fused projection GEMM, 1-D grid of 448 blocks, 128x128 tiles, BK=64,
// global_load_lds staging with XOR-swizzled source (linear dest, swz read).
//   bid < 384 : QKV  — A=xb [4096,512], B=wqkvb [1536,512]^T.
//               cols<1024: RoPE applied in-register (table), bf16 -> qbuf/kbuf
//               cols>=1024: bf16 -> vbuf
//   bid >= 384: KCVC — A=xcb [1022,512] (row-clamped), B=wkvcb [1024,512]^T.
//               col<512 -> kcb, else vcb (bf16), rows <1022
// ---------------------------------------------------------------------------
__global__ __launch_bounds__(256) void proj_gemm(
    const unsigned short* __restrict__ xb, const unsigned short* __restrict__ xcb,
    const unsigned short* __restrict__ wqkvb, const unsigned short* __restrict__ wkvcb,
    const float2* __restrict__ cstab,
    unsigned short* __restrict__ qbuf, unsigned short* __restrict__ kbuf,
    unsigned short* __restrict__ vbuf, unsigned short* __restrict__ kcb,
    unsigned short* __restrict__ vcb) {
  __shared__ short As[128 * 64];
  __shared__ short Bs[128 * 64];
  const int tid = threadIdx.x;
  const int w = tid >> 6, l = tid & 63;
  const int lr = l & 15, lg = l >> 4;

  const int bid = blockIdx.x;
  const bool qkv = (bid < 384);
  const unsigned short* Ap;
  const unsigned short* Bp;
  int bm, bn, Am1;
  if (qkv) {
    Ap = xb; Bp = wqkvb; bm = (bid & 31) * 128; bn = (bid >> 5) * 128; Am1 = 4095;
  } else {
    int r = bid - 384;
    Ap = xcb; Bp = wkvcb; bm = (r & 7) * 128; bn = (r >> 3) * 128; Am1 = 1021;
  }
  const int wm = (w >> 1) * 64, wn = (w & 1) * 64;

  floatx4 acc[4][4];
#pragma unroll
  for (int i = 0; i < 4; ++i)
#pragma unroll
    for (int j = 0; j < 4; ++j) acc[i][j] = 0.f;

  const int trow = tid >> 3;
  const int cs = (tid & 7) ^ (trow & 7);
  size_t aoffs[4];
#pragma unroll
  for (int i = 0; i < 4; ++i) {
    int ar = bm + trow + i * 32;
    if (ar > Am1) ar = Am1;
    aoffs[i] = (size_t)ar * DMODEL + cs * 8;
  }
  const size_t boff = (size_t)(bn + trow) * DMODEL + cs * 8;
  const int ldsbase = (tid & 192) * 8;

  for (int k0 = 0; k0 < DMODEL; k0 += 64) {
    __syncthreads();
#pragma unroll
    for (int i = 0; i < 4; ++i) {
      gld_lds16(Ap + aoffs[i] + k0, As + i * 2048 + ldsbase);
      gld_lds16(Bp + boff + (size_t)i * 32 * DMODEL + k0, Bs + i * 2048 + ldsbase);
    }
    __syncthreads();

#pragma unroll
    for (int kk = 0; kk < 2; ++kk) {
      const int kc16 = kk * 4 + lg;
      short8 a[4], bf[4];
#pragma unroll
      for (int mi = 0; mi < 4; ++mi) {
        int r = wm + mi * 16 + lr;
        a[mi] = *(const short8*)&As[r * 64 + ((kc16 ^ (r & 7)) * 8)];
      }
#pragma unroll
      for (int nj = 0; nj < 4; ++nj) {
        int r = wn + nj * 16 + lr;
        bf[nj] = *(const short8*)&Bs[r * 64 + ((kc16 ^ (r & 7)) * 8)];
      }
#pragma unroll
      for (int mi = 0; mi < 4; ++mi)
#pragma unroll
        for (int nj = 0; nj < 4; ++nj)
          acc[mi][nj] = __builtin_amdgcn_mfma_f32_16x16x32_bf16(
              a[mi], bf[nj], acc[mi][nj], 0, 0, 0);
    }
  }

  if (qkv) {
    if (bn < 1024) {
      // q or k: apply RoPE in-register. Pair (j, j+32) = (acc[.][nj], acc[.][nj+2])
      unsigned short* dst = (bn < 512) ? qbuf : kbuf;
      const int cbase = (bn + wn) & 511;
#pragma unroll
      for (int mi = 0; mi < 4; ++mi) {
#pragma unroll
        for (int i = 0; i < 4; ++i) {
          int row = bm + wm + mi * 16 + lg * 4 + i;
          int p = row & 2047;
#pragma unroll
          for (int nj = 0; nj < 2; ++nj) {
            float2 cssin = cstab[p * 32 + nj * 16 + lr];
            float a = acc[mi][nj][i], b2 = acc[mi][nj + 2][i];
            int cc = cbase + nj * 16 + lr;
            dst[(size_t)row * 512 + cc] = f2bf(a * cssin.x - b2 * cssin.y);
            dst[(size_t)row * 512 + cc + 32] = f2bf(a * cssin.y + b2 * cssin.x);
          }
        }
      }
    } else {
#pragma unroll
      for (int mi = 0; mi < 4; ++mi) {
#pragma unroll
        for (int i = 0; i < 4; ++i) {
          int row = bm + wm + mi * 16 + lg * 4 + i;
#pragma unroll
          for (int nj = 0; nj < 4; ++nj) {
            int col = bn + wn + nj * 16 + lr - 1024;
            vbuf[(size_t)row * 512 + col] = f2bf(acc[mi][nj][i]);
          }
        }
      }
    }
  } else {
    unsigned short* dst = ((bn + wn) < 512) ? kcb : vcb;
    const int cbase = (bn + wn) & 511;
#pragma unroll
    for (int mi = 0; mi < 4; ++mi) {
#pragma unroll
      for (int i = 0; i < 4; ++i) {
        int row = bm + wm + mi * 16 + lg * 4 + i;
        if (row < 1022) {
#pragma unroll
          for (int nj = 0; nj < 4; ++nj)
            dst[(size_t)row * 512 + cbase + nj * 16 + lr] = f2bf(acc[mi][nj][i]);
        }
      }
    }
  }
}

// ---------------------------------------------------------------------------
// Output projection: C[4096,512] = ob[4096,512] x wob[512,512]^T, fp32 out.
// 128x64 tiles -> 256 blocks.
// ---------------------------------------------------------------------------
__global__ __launch_bounds__(256) void wo_gemm(
    const unsigned short* __restrict__ A, const unsigned short* __restrict__ B,
    float* __restrict__ C) {
  __shared__ short As[128 * 64];
  __shared__ short Bs[64 * 64];
  const int tid = threadIdx.x;
  const int w = tid >> 6, l = tid & 63;
  const int lr = l & 15, lg = l >> 4;
  const int bm = blockIdx.x * 128, bn = blockIdx.y * 64;
  const int wm = (w >> 1) * 64, wn = (w & 1) * 32;

  floatx4 acc[4][2];
#pragma unroll
  for (int i = 0; i < 4; ++i)
#pragma unroll
    for (int j = 0; j < 2; ++j) acc[i][j] = 0.f;

  const int trow = tid >> 3;
  const int cs = (tid & 7) ^ (trow & 7);
  const size_t aoff = (size_t)(bm + trow) * DMODEL + cs * 8;
  const size_t boff = (size_t)(bn + trow) * DMODEL + cs * 8;
  const int ldsbase = (tid & 192) * 8;

  for (int k0 = 0; k0 < DMODEL; k0 += 64) {
    __syncthreads();
#pragma unroll
    for (int i = 0; i < 4; ++i)
      gld_lds16(A + aoff + (size_t)i * 32 * DMODEL + k0, As + i * 2048 + ldsbase);
#pragma unroll
    for (int i = 0; i < 2; ++i)
      gld_lds16(B + boff + (size_t)i * 32 * DMODEL + k0, Bs + i * 2048 + ldsbase);
    __syncthreads();

#pragma unroll
    for (int kk = 0; kk < 2; ++kk) {
      const int kc16 = kk * 4 + lg;
      short8 a[4], bf[2];
#pragma unroll
      for (int mi = 0; mi < 4; ++mi) {
        int r = wm + mi * 16 + lr;
        a[mi] = *(const short8*)&As[r * 64 + ((kc16 ^ (r & 7)) * 8)];
      }
#pragma unroll
      for (int nj = 0; nj < 2; ++nj) {
        int r = wn + nj * 16 + lr;
        bf[nj] = *(const short8*)&Bs[r * 64 + ((kc16 ^ (r & 7)) * 8)];
      }
#pragma unroll
      for (int mi = 0; mi < 4; ++mi)
#pragma unroll
        for (int nj = 0; nj < 2; ++nj)
          acc[mi][nj] = __builtin_amdgcn_mfma_f32_16x16x32_bf16(
              a[mi], bf[nj], acc[mi][nj], 0, 0, 0);
    }
  }

#pragma unroll
  for (int mi = 0; mi < 4; ++mi) {
#pragma unroll
    for (int i = 0; i < 4; ++i) {
      int row = bm + wm + mi * 16 + lg * 4 + i;
#pragma unroll
      for (int nj = 0; nj < 2; ++nj)
        C[(size_t)row * 512 + bn + wn + nj * 16 + lr] = acc[mi][nj][i];
    }
  }
}

// ---------------------------------------------------------------------------
// Attention v5: MFMA flash attention, double-buffered staging (1 barrier/tile),
// setprio around MFMA clusters.
// ---------------------------------------------------------------------------
__global__ __launch_bounds__(256, 2) void attn_kernel(
    const unsigned short* __restrict__ qb, const unsigned short* __restrict__ kb,
    const unsigned short* __restrict__ vb, const unsigned short* __restrict__ kcb,
    const unsigned short* __restrict__ vcb, const float* __restrict__ sink,
    unsigned short* __restrict__ ob) {
  __shared__ short Ks[2][64][72];
  __shared__ short Vt[2][64][72];
  __shared__ short Pl[4][16][72];

  const int n = blockIdx.x;
  const int b = n >> 8;
  const int mm = n & 255;
  const int h = mm >> 5;
  int qt = mm & 31;
  if (b) qt = 31 - qt;
  const int q0 = qt * 64;
  const int tid = threadIdx.x;
  const int w = tid >> 6, l = tid & 63;
  const int lr = l & 15, lg = l >> 4;
  const int hoff = h * HD;

  short8 Qa0, Qa1;
  {
    const unsigned short* qrow =
        qb + ((size_t)(b * LSEQ + q0 + w * 16 + lr)) * DMODEL + hoff;
    Qa0 = *(const short8*)(qrow + lg * 8);
    Qa1 = *(const short8*)(qrow + 32 + lg * 8);
  }

  floatx4 Oacc[4];
#pragma unroll
  for (int f = 0; f < 4; ++f) Oacc[f] = 0.f;
  float mrow[4] = {-3.0e38f, -3.0e38f, -3.0e38f, -3.0e38f};
  float lrow[4] = {0.f, 0.f, 0.f, 0.f};

  int ncm = q0 / 4 + 15;
  if (ncm > LC) ncm = LC;
  const int ntc = (ncm + 63) >> 6;
  const int w0 = (q0 > 127) ? (q0 - 127) : 0;
  const int ntw = (q0 + 64 - w0 + 63) >> 6;
  const int ntt = ntc + ntw;

  const int skey = tid >> 2, sd = (tid & 3) * 16;
  const int vkey = (tid & 31) * 2, vd = (tid >> 5) * 8;

  short8 kreg0, kreg1, vreg0, vreg1;

  auto load_tile = [&](int tt) {
    const bool isC = (tt < ntc);
    const int tbase = isC ? tt * 64 : (w0 + (tt - ntc) * 64);
    const unsigned short* Kp = isC ? kcb : kb;
    const unsigned short* Vp = isC ? vcb : vb;
    const int rmax = isC ? (LC - 1) : (LSEQ - 1);
    const size_t brow = isC ? (size_t)(b * LC) : (size_t)(b * LSEQ);
    int kr = tbase + skey;      if (kr > rmax) kr = rmax;
    int vr0 = tbase + vkey;     if (vr0 > rmax) vr0 = rmax;
    int vr1 = tbase + vkey + 1; if (vr1 > rmax) vr1 = rmax;
    const unsigned short* src = Kp + (brow + kr) * DMODEL + hoff + sd;
    kreg0 = *(const short8*)(src);
    kreg1 = *(const short8*)(src + 8);
    vreg0 = *(const short8*)(Vp + (brow + vr0) * DMODEL + hoff + vd);
    vreg1 = *(const short8*)(Vp + (brow + vr1) * DMODEL + hoff + vd);
  };
  auto store_tile = [&](int bsel) {
    *(short8*)&Ks[bsel][skey][sd] = kreg0;
    *(short8*)&Ks[bsel][skey][sd + 8] = kreg1;
#pragma unroll
    for (int j = 0; j < 8; ++j) {
      unsigned pk = (unsigned)(unsigned short)vreg0[j] |
                    ((unsigned)(unsigned short)vreg1[j] << 16);
      *(unsigned*)&Vt[bsel][vd + j][vkey] = pk;
    }
  };

  load_tile(0);

  for (int tt = 0; tt < ntt; ++tt) {
    const int bsel = tt & 1;
    store_tile(bsel);
    if (tt + 1 < ntt) load_tile(tt + 1);
    __syncthreads();

    const bool isC = (tt < ntc);
    const int tbase = isC ? tt * 64 : (w0 + (tt - ntc) * 64);

    // ---- S = Q K^T ----
    floatx4 S[4];
    __builtin_amdgcn_s_setprio(1);
#pragma unroll
    for (int f = 0; f < 4; ++f) {
      floatx4 acc = 0.f;
      short8 kf0 = *(const short8*)&Ks[bsel][f * 16 + lr][lg * 8];
      short8 kf1 = *(const short8*)&Ks[bsel][f * 16 + lr][32 + lg * 8];
      acc = __builtin_amdgcn_mfma_f32_16x16x32_bf16(Qa0, kf0, acc, 0, 0, 0);
      acc = __builtin_amdgcn_mfma_f32_16x16x32_bf16(Qa1, kf1, acc, 0, 0, 0);
      S[f] = acc;
    }
    __builtin_amdgcn_s_setprio(0);

    // ---- mask + scale + online softmax ----
    float tmax[4] = {-3.0e38f, -3.0e38f, -3.0e38f, -3.0e38f};
#pragma unroll
    for (int f = 0; f < 4; ++f) {
      const int key = tbase + f * 16 + lr;
#pragma unroll
      for (int i = 0; i < 4; ++i) {
        const int p = q0 + w * 16 + lg * 4 + i;
        bool valid;
        if (isC) valid = (key <= LC - 1) && (p >= key * 4 + 7);
        else     valid = (p >= key) && (p - key < WINDOW);
        float s = valid ? S[f][i] * 0.125f : -3.0e38f;
        S[f][i] = s;
        tmax[i] = fmaxf(tmax[i], s);
      }
    }
#pragma unroll
    for (int i = 0; i < 4; ++i) {
      tmax[i] = fmaxf(tmax[i], __shfl_xor(tmax[i], 1));
      tmax[i] = fmaxf(tmax[i], __shfl_xor(tmax[i], 2));
      tmax[i] = fmaxf(tmax[i], __shfl_xor(tmax[i], 4));
      tmax[i] = fmaxf(tmax[i], __shfl_xor(tmax[i], 8));
    }
    float r[4];
#pragma unroll
    for (int i = 0; i < 4; ++i) {
      float mn = fmaxf(mrow[i], tmax[i]);
      r[i] = __expf(mrow[i] - mn);
      mrow[i] = mn;
    }
#pragma unroll
    for (int f = 0; f < 4; ++f) {
#pragma unroll
      for (int i = 0; i < 4; ++i) Oacc[f][i] *= r[i];
    }
    float lsum[4] = {0.f, 0.f, 0.f, 0.f};
#pragma unroll
    for (int f = 0; f < 4; ++f) {
#pragma unroll
      for (int i = 0; i < 4; ++i) {
        float ee = (S[f][i] > -1.0e38f) ? __expf(S[f][i] - mrow[i]) : 0.f;
        lsum[i] += ee;
        Pl[w][lg * 4 + i][f * 16 + lr] = (short)f2bf(ee);
      }
    }
#pragma unroll
    for (int i = 0; i < 4; ++i) {
      float t = lsum[i];
      t += __shfl_xor(t, 1); t += __shfl_xor(t, 2);
      t += __shfl_xor(t, 4); t += __shfl_xor(t, 8);
      lrow[i] = lrow[i] * r[i] + t;
    }
    asm volatile("s_waitcnt lgkmcnt(0)" ::: "memory");

    // ---- PV ----
    __builtin_amdgcn_s_setprio(1);
#pragma unroll
    for (int c = 0; c < 2; ++c) {
      short8 Pa = *(const short8*)&Pl[w][lr][c * 32 + lg * 8];
#pragma unroll
      for (int f = 0; f < 4; ++f) {
        short8 Vf = *(const short8*)&Vt[bsel][f * 16 + lr][c * 32 + lg * 8];
        Oacc[f] = __builtin_amdgcn_mfma_f32_16x16x32_bf16(Pa, Vf, Oacc[f], 0, 0, 0);
      }
    }
    __builtin_amdgcn_s_setprio(0);
  }

  const float snk = sink[h];
  float osc[4];
#pragma unroll
  for (int i = 0; i < 4; ++i) {
    float ms = fmaxf(mrow[i], snk);
    float sc = __expf(mrow[i] - ms);
    float li = lrow[i] * sc + __expf(snk - ms);
    osc[i] = sc / li;
  }
#pragma unroll
  for (int f = 0; f < 4; ++f) {
#pragma unroll
    for (int i = 0; i < 4; ++i) {
      size_t row = (size_t)(b * LSEQ + q0 + w * 16 + lg * 4 + i);
      ob[row * DMODEL + hoff + f * 16 + lr] = f2bf(Oacc[f][i] * osc[i]);
    }
  }
}

// ---------------------------------------------------------------------------
// Launch
// ---------------------------------------------------------------------------
extern "C" void kernel_launch(void* const* d_in, const int* in_sizes, int n_in,
                              void* d_out, int out_size, void* d_ws, size_t ws_size,
                              hipStream_t stream) {
  const float* x    = (const float*)d_in[0];
  const float* wq   = (const float*)d_in[1];
  const float* wk   = (const float*)d_in[2];
  const float* wv   = (const float*)d_in[3];
  const float* wo   = (const float*)d_in[4];
  const float* wkc  = (const float*)d_in[5];
  const float* wvc  = (const float*)d_in[6];
  const float* gate = (const float*)d_in[7];
  const float* sink = (const float*)d_in[8];
  float* out = (float*)d_out;

  const int BL  = BATCH * LSEQ;   // 4096
  const int BLC = BATCH * LC;     // 1022
  const int NX  = BATCH * LSEQ * DMODEL;   // 2097152
  const int NW  = DMODEL * DMODEL;         // 262144

  char* wp = (char*)d_ws;
  auto carve = [&](size_t bytes) {
    char* r = wp;
    wp += (bytes + 255) & ~(size_t)255;
    return r;
  };
  unsigned short* qbuf = (unsigned short*)carve((size_t)BL * DMODEL * 2);
  unsigned short* kbuf = (unsigned short*)carve((size_t)BL * DMODEL * 2);
  unsigned short* vbuf = (unsigned short*)carve((size_t)BL * DMODEL * 2);
  unsigned short* kcb  = (unsigned short*)carve((size_t)BLC * DMODEL * 2);
  unsigned short* vcb  = (unsigned short*)carve((size_t)BLC * DMODEL * 2);
  unsigned short* xb   = (unsigned short*)carve((size_t)NX * 2);
  unsigned short* xcb  = (unsigned short*)carve((size_t)BLC * DMODEL * 2);
  unsigned short* ob   = (unsigned short*)carve((size_t)BL * DMODEL * 2);
  unsigned short* wqkvb = (unsigned short*)carve((size_t)NW * 3 * 2);
  unsigned short* wkvcb = (unsigned short*)carve((size_t)NW * 2 * 2);
  unsigned short* wob   = (unsigned short*)carve((size_t)NW * 2);
  float2* cstab = (float2*)carve((size_t)2048 * 32 * sizeof(float2));

  // 1) conversions + xc + cos/sin table (1113856 items = 4351 blocks)
  conv_all<<<4351, 256, 0, stream>>>(x, wq, wk, wv, wkc, wvc, wo, gate,
                                     xb, wqkvb, wkvcb, wob, xcb, cstab);

  // 2) all projections + fused RoPE (448 blocks)
  proj_gemm<<<448, 256, 0, stream>>>(xb, xcb, wqkvb, wkvcb, cstab,
                                     qbuf, kbuf, vbuf, kcb, vcb);

  // 3) attention
  attn_kernel<<<BATCH * NHEADS * (LSEQ / 64), 256, 0, stream>>>(
      qbuf, kbuf, vbuf, kcb, vcb, sink, ob);

  // 4) output projection
  wo_gemm<<<dim3(BL / 128, DMODEL / 64), 256, 0, stream>>>(ob, wob, out);
}